// Round 7
// baseline (1024.647 us; speedup 1.0000x reference)
//
#include <hip/hip_runtime.h>
#include <cstdint>
#include <cstddef>

constexpr int IMG_H = 800, IMG_W = 1216;
constexpr int FH = 200, FW = 304;
constexpr int FHW = FH * FW;            // 60800
constexpr int NANCH = 3 * FHW;          // 182400
constexpr int PRE = 1000, POST = 100;
constexpr float NMS_T = 0.7f;
constexpr int QH = 803, QW = 1220;      // padded split image dims (c4 inner)

// ---------------- workspace layout (BYTE offsets) ----------------
constexpr size_t B_FEATH = 0;                       // bf16 60800*256
constexpr size_t B_FEATL = 31129600;                // bf16
constexpr size_t B_T     = 62259200;                // overlay region
constexpr size_t B_S1H   = B_T;                     // stem1 hi plane 60800*64*2
constexpr size_t B_S1L   = B_T + 7782400;
constexpr size_t B_TH    = B_T;                     // rpn t hi plane 60800*256*2
constexpr size_t B_TL    = B_T + 31129600;          // rpn t lo plane
constexpr size_t B_PART  = B_T;                     // fp32 28*128*1024 (box head)
constexpr size_t B_M0H   = B_T;                     // mask hi planes 19600*256*2 each
constexpr size_t B_MP1H  = B_T + 10035200;
constexpr size_t B_MP2H  = B_T + 20070400;
constexpr size_t B_DP    = B_T + 30105600;          // fp32 8*19600
constexpr size_t B_RPNO  = 124518400;               // fp32 60800*16
constexpr size_t B_OBJ   = 128409600;               // fp32 182400
constexpr size_t B_BOX   = 129139200;               // fp32 182400*4
constexpr size_t B_HIST  = 132057600;               // u32 65536
constexpr size_t B_MISC  = 132319744;               // 64KB misc
constexpr size_t B_POOL  = 132385280;               // fp32 100*49*256 (cand + iomask overlay early)
constexpr size_t B_X1    = 137402880;               // fp32 100*1024
constexpr size_t B_X2    = 137812480;
constexpr size_t B_LOG   = 138222080;               // fp32 100*128
constexpr size_t B_WRPNH = 138273280;               // u16 split rpn-head weights (unused now, kept)
constexpr size_t B_WFC2  = 138404352;               // fp32 1024*1024
constexpr size_t B_WCLS  = 142598656;               // fp32 1024*128
constexpr size_t B_WFC1  = 143122944;               // fp32 12544*1024
constexpr size_t B_WSP   = 194503168;               // split weights (bf16)
constexpr size_t B_WSP_S2  = B_WSP;                 // 576*256*4
constexpr size_t B_WSP_RPN = B_WSP_S2 + 589824;     // 2304*256*4
constexpr size_t B_WSP_M1  = B_WSP_RPN + 2359296;   // 4x 1179648
constexpr size_t B_WSP_DC  = B_WSP_M1 + 4 * 1179648;
constexpr size_t B_IMGH  = B_WSP_DC + 1048576;
constexpr size_t B_IMGL  = B_IMGH + 7837280;
constexpr size_t B_WS1   = B_IMGL + 7837280;        // stem1 split weights 114688 B
// MISC sublayout
constexpr size_t B_CNT  = B_MISC + 0;
constexpr size_t B_CUT  = B_MISC + 4;
constexpr size_t B_ZBUF = B_MISC + 256;             // 256B zeros
constexpr size_t B_TOPS = B_MISC + 512;             // 1000 f
constexpr size_t B_TOPB = B_MISC + 4608;            // 4000 f
constexpr size_t B_KEEP = B_MISC + 20608;           // 100 i
constexpr size_t B_VALI = B_MISC + 21008;
constexpr size_t B_VALF = B_MISC + 21408;
constexpr size_t B_ROIS = B_MISC + 21808;           // 400 f
constexpr size_t B_LAB  = B_MISC + 23408;           // 100 i
// d_out offsets (floats)
constexpr size_t OUT_ROIS = 0, OUT_LABS = 400, OUT_MASK = 500, OUT_SC = 78900;

using f32x4 = __attribute__((ext_vector_type(4))) float;
using s16x8 = __attribute__((ext_vector_type(8))) short;
typedef unsigned short u16;

__device__ __forceinline__ u16 bf16r(float f) {
    unsigned u = __float_as_uint(f);
    return (u16)((u + 0x7FFFu + ((u >> 16) & 1u)) >> 16);
}
__device__ __forceinline__ float bff(u16 h) { return __uint_as_float(((unsigned)h) << 16); }

__device__ __forceinline__ unsigned int sortable_f(float f) {
    unsigned int u = __float_as_uint(f);
    return (u & 0x80000000u) ? ~u : (u | 0x80000000u);
}

// conv3x3 split pack helper
__device__ __forceinline__ void packsplit3_body(int e, const float* __restrict__ w, u16* __restrict__ dst,
                                                int C, int clog2, int nks) {
    int j = e & 7, col = (e >> 3) & 127, kblk = (e >> 10) & 3;
    int g = e >> 12; int ks = g % nks; int nt = g / nks;
    int k = ks * 32 + kblk * 8 + j;
    int o = nt * 128 + col;
    int c = k & (C - 1); int q = k >> clog2;
    int ky = q / 3, kx = q - ky * 3;
    float v = w[(size_t)(o * C + c) * 9 + ky * 3 + kx];
    u16 h = bf16r(v); u16 l = bf16r(v - bff(h));
    size_t base = (size_t)(nt * nks + ks) * 8192 + kblk * 1024 + col * 8 + j;
    dst[base] = h; dst[base + 4096] = l;
}

// ---------------- ALL init + weight packing in ONE kernel ----------------
__global__ __launch_bounds__(256) void k_packs(
    const float* __restrict__ image, const float* __restrict__ stem_w1, const float* __restrict__ stem_w2,
    const float* __restrict__ rpn_w, const float* __restrict__ rpn_cls_w, const float* __restrict__ rpn_box_w,
    const float* __restrict__ fc1_w, const float* __restrict__ fc2_w, const float* __restrict__ cls_w,
    const float* __restrict__ mw0, const float* __restrict__ mw1, const float* __restrict__ mw2,
    const float* __restrict__ mw3, const float* __restrict__ wd,
    unsigned int* __restrict__ hist, unsigned int* __restrict__ cnt, unsigned int* __restrict__ zbuf,
    float* __restrict__ wfc2, float* __restrict__ wcls, float* __restrict__ wfc1,
    u16* __restrict__ wsp_s2, u16* __restrict__ wsp_rpn, u16* __restrict__ wsp_m, u16* __restrict__ wsp_dc,
    u16* __restrict__ wrpnh, u16* __restrict__ ws1, u16* __restrict__ imgh, u16* __restrict__ imgl)
{
    __shared__ float tile[64][50];
    int b = blockIdx.x, t = threadIdx.x;
    if (b < 256) {
        int i = b * 256 + t;
        if (i < 65536) hist[i] = 0u;
        if (i < 64) zbuf[i] = 0u;
        if (i == 0) cnt[0] = 0u;
    } else if (b < 4352) {          // fc2^T
        int e = (b - 256) * 256 + t;
        int k = e >> 10, n = e & 1023;
        wfc2[e] = fc2_w[(size_t)n * 1024 + k];
    } else if (b < 4864) {          // cls^T pad 128
        int e = (b - 4352) * 256 + t;
        int k = e >> 7, n = e & 127;
        wcls[e] = (n < 81) ? cls_w[(size_t)n * 1024 + k] : 0.f;
    } else if (b < 8960) {          // fc1 transpose
        int bb = b - 4864;
        int c = bb >> 4, n0 = (bb & 15) * 64;
        for (int e = t; e < 64 * 49; e += 256) {
            int nn = e / 49, ss = e - nn * 49;
            tile[nn][ss] = fc1_w[(size_t)(n0 + nn) * 12544 + c * 49 + ss];
        }
        __syncthreads();
        for (int e = t; e < 49 * 64; e += 256) {
            int ss = e >> 6, nn = e & 63;
            wfc1[(size_t)(ss * 256 + c) * 1024 + n0 + nn] = tile[nn][ss];
        }
    } else if (b < 9536) {          // stem2 split
        packsplit3_body((b - 8960) * 256 + t, stem_w2, wsp_s2, 64, 6, 18);
    } else if (b < 11840) {         // rpn split
        packsplit3_body((b - 9536) * 256 + t, rpn_w, wsp_rpn, 256, 8, 72);
    } else if (b < 21056) {         // mask convs x4
        int bb = b - 11840;
        int z = bb / 2304;
        const float* w = (z == 0) ? mw0 : (z == 1) ? mw1 : (z == 2) ? mw2 : mw3;
        packsplit3_body((bb - z * 2304) * 256 + t, w, wsp_m + (size_t)z * 1179648, 256, 8, 72);
    } else if (b < 22080) {         // deconv fused
        int e = (b - 21056) * 256 + t;
        int j = e & 7, col = (e >> 3) & 127, kblk = (e >> 10) & 3;
        int g = e >> 12; int ks = g & 7; int nt = g >> 3;
        int k = ks * 32 + kblk * 8 + j;
        int n = nt * 128 + col;
        int pyx = n >> 8, o = n & 255;
        int py = pyx >> 1, px = pyx & 1;
        float v = wd[(size_t)(o * 256 + k) * 4 + (1 - py) * 2 + (1 - px)];
        u16 h = bf16r(v); u16 l = bf16r(v - bff(h));
        size_t base = (size_t)(nt * 8 + ks) * 8192 + kblk * 1024 + col * 8 + j;
        wsp_dc[base] = h; wsp_dc[base + 4096] = l;
    } else if (b < 22208) {         // rpn head split (unused, kept for range stability)
        int e = (b - 22080) * 256 + t;
        int j = e & 7, col = (e >> 3) & 127, kblk = (e >> 10) & 3, ks = e >> 12;
        int k = ks * 32 + kblk * 8 + j;
        float v = 0.f;
        if (col < 3) v = rpn_cls_w[col * 256 + k];
        else if (col < 15) v = rpn_box_w[(col - 3) * 256 + k];
        u16 h = bf16r(v); u16 l = bf16r(v - bff(h));
        size_t base = (size_t)ks * 8192 + kblk * 1024 + col * 8 + j;
        wrpnh[base] = h; wrpnh[base + 4096] = l;
    } else if (b < 22320) {         // stem1 weights split
        int e = (b - 22208) * 256 + t;
        int j = e & 7, col = (e >> 3) & 127, kblk = (e >> 10) & 3, ks = e >> 12;
        int k = ks * 32 + kblk * 8 + j;
        int ky = k >> 5, kx = (k >> 2) & 7, c = k & 3;
        float v = 0.f;
        if (kx < 7 && c < 3 && col < 64) v = stem_w1[(((size_t)col * 3 + c) * 7 + ky) * 7 + kx];
        u16 h = bf16r(v); u16 l = bf16r(v - bff(h));
        size_t base = (size_t)ks * 8192 + kblk * 1024 + col * 8 + j;
        ws1[base] = h; ws1[base + 4096] = l;
    } else {                        // padded image split
        int e = (b - 22320) * 256 + t;
        if (e < QH * QW * 4) {
            int c = e & 3; int p = e >> 2;
            int xx = p % QW; int yy = p / QW;
            int iy = yy - 1, ix = xx - 1;
            float v = 0.f;
            if (c < 3 && (unsigned)iy < (unsigned)IMG_H && (unsigned)ix < (unsigned)IMG_W)
                v = image[((size_t)c * IMG_H + iy) * IMG_W + ix];
            u16 h = bf16r(v);
            imgh[e] = h; imgl[e] = bf16r(v - bff(h));
        }
    }
}

// ---------------- split-bf16 MFMA GEMM (implicit conv), 16x16x32 inner (r3 structure) ----------------
// A,B staged via LDS, single-buffered, 2 barriers per K-step — measured-best structure.
// AMODE 0: flat A rows (stride Kflat); 1: 3x3 SAME im2col HWC (C=1<<clog2); 2: stem1 7x7 s4
// TERMS 3: ah*bh+ah*bl+al*bh ; 2: ah*bh+ah*bl ; 1: ah*bh
// OUTK: 0 fp32, 1 split hi+lo, 3 hi only  (all guard n<nstore)
// EPI 0: store; EPI 2: fused deconv mask-pred partial
template<int AMODE, int EPI, int RELU, int OUTK, int TERMS>
__global__ __launch_bounds__(256) void k_mfma(
    const u16* __restrict__ Ahi, const u16* __restrict__ Alo,
    const u16* __restrict__ Bsp,
    float* __restrict__ outF, u16* __restrict__ outH, u16* __restrict__ outL,
    int ostride, int nstore,
    int M, int H, int W, int clog2, int nks, int Kflat,
    const u16* __restrict__ zb,
    const int* __restrict__ labels, const float* __restrict__ wp,
    float* __restrict__ dpart, int Mtot)
{
    constexpr int APL = (TERMS == 3) ? 8192 : 4096;
    constexpr int BPL = (TERMS >= 2) ? 8192 : 4096;
    __shared__ u16 Al[APL];
    __shared__ u16 Bl[BPL];
    __shared__ float scr[2][128];
    const int tid = threadIdx.x;
    // XCD-contiguous bijective swizzle (m204)
    int lin = blockIdx.y * gridDim.x + blockIdx.x;
    int nb = gridDim.x * gridDim.y;
    int qq = nb >> 3, rr = nb & 7;
    int xcd = lin & 7, rkk = lin >> 3;
    int nlin = (xcd < rr ? xcd * (qq + 1) : rr * (qq + 1) + (xcd - rr) * qq) + rkk;
    const int nt = nlin % gridDim.x, mt = nlin / gridDim.x;

    const int m0 = mt * 128, n0 = nt * 128;
    const int w = tid >> 6, lane = tid & 63;
    const int wr = w >> 1, wc = w & 1;
    const int lhi = lane >> 4, llo = lane & 15;

    const int row = tid & 127;
    const int kb0 = tid >> 7;     // 0 or 1
    const int m = m0 + row;
    const bool mv = (m < M);
    int pbase = 0, pi = 0, pj = 0;
    if (AMODE >= 1) {
        int mm = mv ? m : 0;
        int HW = H * W;
        int b = mm / HW; int r2 = mm - b * HW;
        pi = r2 / W; pj = r2 - pi * W;
        pbase = b * HW;
    }

    f32x4 acc[4][4];
#pragma unroll
    for (int i = 0; i < 4; ++i)
#pragma unroll
        for (int j = 0; j < 4; ++j) acc[i][j] = (f32x4)(0.f);

    int4 rA0, rA1, rA2, rA3, rB0, rB1, rB2, rB3;

    auto loadA = [&](int ks) {
        const u16 *sh, *sl = nullptr;
        if (AMODE == 1) {
            int k0 = ks * 32; int q = k0 >> clog2; int c0 = k0 & ((1 << clog2) - 1);
            int ky = q / 3, kx = q - ky * 3;
            int yy = pi + ky - 1, xx = pj + kx - 1;
            bool ok = mv && (unsigned)yy < (unsigned)H && (unsigned)xx < (unsigned)W;
            size_t off = (((size_t)(pbase + yy * W + xx)) << clog2) + c0 + kb0 * 8;
            sh = ok ? Ahi + off : zb;
            if (TERMS == 3) sl = ok ? Alo + off : zb;
        } else if (AMODE == 2) {
            int kk = ks * 32 + kb0 * 8;
            int ky = kk >> 5;
            int kx0 = (kk >> 2) & 7;
            size_t off = ((size_t)(pi * 4 + ky) * QW + pj * 4 + kx0) * 4;
            sh = Ahi + off;
            if (TERMS == 3) sl = Alo + off;
        } else {
            size_t off = (size_t)(mv ? m : 0) * Kflat + ks * 32 + kb0 * 8;
            sh = mv ? Ahi + off : zb;
            if (TERMS == 3) sl = mv ? Alo + off : zb;
        }
        rA0 = *(const int4*)sh;  rA1 = *(const int4*)(sh + 16);
        if (TERMS == 3) { rA2 = *(const int4*)sl;  rA3 = *(const int4*)(sl + 16); }
    };
    auto loadB = [&](int ks) {
        const u16* bs = Bsp + ((size_t)(nt * nks + ks)) * 8192;
        rB0 = *(const int4*)(bs + (size_t)tid * 8);
        rB1 = *(const int4*)(bs + (size_t)(tid + 256) * 8);
        if (TERMS >= 2) {
            rB2 = *(const int4*)(bs + (size_t)(tid + 512) * 8);
            rB3 = *(const int4*)(bs + (size_t)(tid + 768) * 8);
        }
    };
    auto stash = [&]() {
        *(int4*)&Al[(size_t)((kb0    ) * 128 + row) * 8] = rA0;
        *(int4*)&Al[(size_t)((kb0 + 2) * 128 + row) * 8] = rA1;
        if (TERMS == 3) {
            *(int4*)&Al[4096 + (size_t)((kb0    ) * 128 + row) * 8] = rA2;
            *(int4*)&Al[4096 + (size_t)((kb0 + 2) * 128 + row) * 8] = rA3;
        }
        *(int4*)&Bl[(size_t)tid * 8] = rB0;
        *(int4*)&Bl[(size_t)(tid + 256) * 8] = rB1;
        if (TERMS >= 2) {
            *(int4*)&Bl[(size_t)(tid + 512) * 8] = rB2;
            *(int4*)&Bl[(size_t)(tid + 768) * 8] = rB3;
        }
    };

    loadA(0); loadB(0);
    for (int ks = 0; ks < nks; ++ks) {
        if (ks) __syncthreads();
        stash();
        __syncthreads();
        if (ks + 1 < nks) { loadA(ks + 1); loadB(ks + 1); }
        s16x8 fAh[4], fAl2[4], fBh[4], fBl[4];
#pragma unroll
        for (int i = 0; i < 4; ++i) {
            int ar = wr * 64 + i * 16 + llo;
            fAh[i]  = *(const s16x8*)&Al[(size_t)(lhi * 128 + ar) * 8];
            if (TERMS == 3) fAl2[i] = *(const s16x8*)&Al[4096 + (size_t)(lhi * 128 + ar) * 8];
            int bc = wc * 64 + i * 16 + llo;
            fBh[i] = *(const s16x8*)&Bl[(size_t)(lhi * 128 + bc) * 8];
            if (TERMS >= 2) fBl[i] = *(const s16x8*)&Bl[4096 + (size_t)(lhi * 128 + bc) * 8];
        }
#pragma unroll
        for (int i = 0; i < 4; ++i)
#pragma unroll
            for (int j = 0; j < 4; ++j) {
                acc[i][j] = __builtin_amdgcn_mfma_f32_16x16x32_bf16(fAh[i],  fBh[j], acc[i][j], 0, 0, 0);
                if (TERMS >= 2)
                    acc[i][j] = __builtin_amdgcn_mfma_f32_16x16x32_bf16(fAh[i],  fBl[j], acc[i][j], 0, 0, 0);
                if (TERMS == 3)
                    acc[i][j] = __builtin_amdgcn_mfma_f32_16x16x32_bf16(fAl2[i], fBh[j], acc[i][j], 0, 0, 0);
            }
    }

    if (EPI == 0) {
#pragma unroll
        for (int i = 0; i < 4; ++i)
#pragma unroll
            for (int j = 0; j < 4; ++j) {
                f32x4 v = acc[i][j];
                int n = n0 + wc * 64 + j * 16 + llo;
                if (n >= nstore) continue;
#pragma unroll
                for (int r = 0; r < 4; ++r) {
                    int mm = m0 + wr * 64 + i * 16 + lhi * 4 + r;
                    if (mm < M) {
                        float val = RELU ? fmaxf(v[r], 0.f) : v[r];
                        if constexpr (OUTK == 0) {
                            outF[(size_t)mm * ostride + n] = val;
                        } else if constexpr (OUTK == 1) {
                            u16 h = bf16r(val);
                            outH[(size_t)mm * ostride + n] = h;
                            outL[(size_t)mm * ostride + n] = bf16r(val - bff(h));
                        } else {
                            outH[(size_t)mm * ostride + n] = bf16r(val);
                        }
                    }
                }
            }
    } else {
        // EPI2: deconv + per-label mask-pred dot
#pragma unroll
        for (int i = 0; i < 4; ++i) {
            int mrow = m0 + wr * 64 + i * 16 + lhi * 4;
            int b = mrow / 196; if (b > 99) b = 99;
            int lab = labels[b];
            float wv[4];
#pragma unroll
            for (int j = 0; j < 4; ++j)
                wv[j] = wp[lab * 256 + ((n0 + wc * 64 + j * 16 + llo) & 255)];
#pragma unroll
            for (int r = 0; r < 4; ++r) {
                float s = 0.f;
#pragma unroll
                for (int j = 0; j < 4; ++j) s = fmaf(fmaxf(acc[i][j][r], 0.f), wv[j], s);
                s += __shfl_xor(s, 1, 64); s += __shfl_xor(s, 2, 64);
                s += __shfl_xor(s, 4, 64); s += __shfl_xor(s, 8, 64);
                if (llo == 0) scr[wc][wr * 64 + i * 16 + lhi * 4 + r] = s;
            }
        }
        __syncthreads();
        if (tid < 128) {
            int mm = m0 + tid;
            if (mm < M) dpart[(size_t)nt * Mtot + mm] = scr[0][tid] + scr[1][tid];
        }
    }
}

// ---------------- rpn head: 1x1 conv, 15 outputs, plain VALU (full fp32 from hi+lo) ----------------
__global__ __launch_bounds__(256) void k_rpnhead(const u16* __restrict__ th, const u16* __restrict__ tl,
                                                 const float* __restrict__ wcls, const float* __restrict__ wbox,
                                                 float* __restrict__ rpno) {
    __shared__ float W[15][256];
    int t = threadIdx.x;
    for (int e = t; e < 15 * 256; e += 256) {
        int o = e >> 8, k = e & 255;
        W[o][k] = (o < 3) ? wcls[o * 256 + k] : wbox[(o - 3) * 256 + k];
    }
    __syncthreads();
    int p = blockIdx.x * 256 + t;
    if (p >= FHW) return;
    const u16* ph = th + (size_t)p * 256;
    const u16* pl = tl + (size_t)p * 256;
    float acc[15];
#pragma unroll
    for (int o = 0; o < 15; ++o) acc[o] = 0.f;
    for (int k0 = 0; k0 < 256; k0 += 8) {
        s16x8 vh = *(const s16x8*)(ph + k0);
        s16x8 vl = *(const s16x8*)(pl + k0);
        float v[8];
#pragma unroll
        for (int j = 0; j < 8; ++j) v[j] = bff((u16)vh[j]) + bff((u16)vl[j]);
#pragma unroll
        for (int o = 0; o < 15; ++o) {
            float s = acc[o];
#pragma unroll
            for (int j = 0; j < 8; ++j) s = fmaf(v[j], W[o][k0 + j], s);
            acc[o] = s;
        }
    }
    float* rp = rpno + (size_t)p * 16;
#pragma unroll
    for (int o = 0; o < 15; ++o) rp[o] = acc[o];
    rp[15] = 0.f;
}

// ---------------- generic fp32 tile GEMM (fc head, split-K) ----------------
template<int EPI, int RELU>
__global__ __launch_bounds__(256, 2) void k_gemm(
    const float* __restrict__ Ap, const float* __restrict__ Bp,
    float* __restrict__ outp, int out_stride, int Nstore,
    int M, int Npad, int ksteps, int Kflat)
{
    __shared__ float As[16][128];
    __shared__ float Bs[16][128];
    const int tid = threadIdx.x;
    const int nt = blockIdx.x, mt = blockIdx.y, kz = blockIdx.z;
    const int m0 = mt * 128, n0 = nt * 128;
    const int ty = tid >> 4, tx = tid & 15;
    const int am = tid >> 1;
    const int kl = (tid & 1) << 3;
    const int m_g = m0 + am;
    const bool mval = (m_g < M);
    const float* aRow = Ap + (size_t)(mval ? m_g : 0) * Kflat;
    float acc[8][8];
#pragma unroll
    for (int i = 0; i < 8; ++i)
#pragma unroll
        for (int j = 0; j < 8; ++j) acc[i][j] = 0.f;
    const int kbeg = kz * ksteps * 16;
    for (int s = 0; s < ksteps; ++s) {
        const int k0 = kbeg + s * 16;
        float4 v0, v1;
        const int kk = k0 + kl;
        if (mval) {
            v0 = *(const float4*)(aRow + kk);
            v1 = *(const float4*)(aRow + kk + 4);
        } else { v0 = make_float4(0.f, 0.f, 0.f, 0.f); v1 = v0; }
        As[kl + 0][am] = v0.x; As[kl + 1][am] = v0.y; As[kl + 2][am] = v0.z; As[kl + 3][am] = v0.w;
        As[kl + 4][am] = v1.x; As[kl + 5][am] = v1.y; As[kl + 6][am] = v1.z; As[kl + 7][am] = v1.w;
        {
            const float* p = Bp + (size_t)(k0 + ty) * Npad + n0 + (tx << 3);
            float4 b0 = *(const float4*)p;
            float4 b1 = *(const float4*)(p + 4);
            *(float4*)&Bs[ty][(tx << 3)] = b0;
            *(float4*)&Bs[ty][(tx << 3) + 4] = b1;
        }
        __syncthreads();
#pragma unroll
        for (int k = 0; k < 16; ++k) {
            float4 a0 = *(const float4*)&As[k][(ty << 3)];
            float4 a1 = *(const float4*)&As[k][(ty << 3) + 4];
            float4 b0 = *(const float4*)&Bs[k][(tx << 2)];
            float4 b1 = *(const float4*)&Bs[k][64 + (tx << 2)];
            float av[8] = {a0.x, a0.y, a0.z, a0.w, a1.x, a1.y, a1.z, a1.w};
            float bv[8] = {b0.x, b0.y, b0.z, b0.w, b1.x, b1.y, b1.z, b1.w};
#pragma unroll
            for (int i = 0; i < 8; ++i)
#pragma unroll
                for (int j = 0; j < 8; ++j)
                    acc[i][j] = fmaf(av[i], bv[j], acc[i][j]);
        }
        __syncthreads();
    }
#pragma unroll
    for (int i = 0; i < 8; ++i) {
        int ml = (ty << 3) + i;
        int mm = (EPI == 1) ? (kz * 128 + ml) : (m0 + ml);
        bool mok = (EPI == 1) ? true : (mm < M);
        if (!mok) continue;
        float4 v0 = make_float4(acc[i][0], acc[i][1], acc[i][2], acc[i][3]);
        float4 v1 = make_float4(acc[i][4], acc[i][5], acc[i][6], acc[i][7]);
        if (RELU) {
            v0.x = fmaxf(v0.x, 0.f); v0.y = fmaxf(v0.y, 0.f); v0.z = fmaxf(v0.z, 0.f); v0.w = fmaxf(v0.w, 0.f);
            v1.x = fmaxf(v1.x, 0.f); v1.y = fmaxf(v1.y, 0.f); v1.z = fmaxf(v1.z, 0.f); v1.w = fmaxf(v1.w, 0.f);
        }
        int c0 = n0 + (tx << 2), c1 = n0 + 64 + (tx << 2);
        if (c0 < Nstore) *(float4*)(outp + (size_t)mm * out_stride + c0) = v0;
        if (c1 < Nstore) *(float4*)(outp + (size_t)mm * out_stride + c1) = v1;
    }
}

// ---------------- split-K reduce ----------------
__global__ __launch_bounds__(256) void k_reduce(const float* __restrict__ part, float* __restrict__ out, int M, int N, int ks, int relu) {
    int e = blockIdx.x * 256 + threadIdx.x;
    if (e >= M * N) return;
    int m = e / N, n = e - m * N;
    float s = 0.f;
    for (int k = 0; k < ks; ++k) s += part[((size_t)k * 128 + m) * N + n];
    if (relu) s = fmaxf(s, 0.f);
    out[(size_t)m * N + n] = s;
}

// ---------------- rpn decode + hist (merged) ----------------
__global__ __launch_bounds__(256) void k_decodehist(const float* __restrict__ rpno, float* __restrict__ obj,
                                                    float* __restrict__ boxes, unsigned int* __restrict__ hist) {
    int e = blockIdx.x * 256 + threadIdx.x;
    if (e >= NANCH) return;
    int a = e / FHW; int p = e - a * FHW;
    int y = p / FW, x = p - y * FW;
    const float* rp = rpno + (size_t)p * 16;
    float objv = rp[a];
    float dx = rp[3 + a * 4 + 0], dy = rp[3 + a * 4 + 1];
    float dw = rp[3 + a * 4 + 2], dh = rp[3 + a * 4 + 3];
    float sz = (a == 0) ? 32.f : ((a == 1) ? 64.f : 128.f);
    float cxa = (x + 0.5f) * 4.f, cya = (y + 0.5f) * 4.f;
    const float clipv = 4.135166556742356f;
    dw = fminf(dw, clipv); dh = fminf(dh, clipv);
    float cx = dx * sz + cxa, cy = dy * sz + cya;
    float wv = expf(dw) * sz, hv = expf(dh) * sz;
    float x1 = fminf(fmaxf(cx - wv * 0.5f, 0.f), 1215.f);
    float y1 = fminf(fmaxf(cy - hv * 0.5f, 0.f), 799.f);
    float x2 = fminf(fmaxf(cx + wv * 0.5f, 0.f), 1215.f);
    float y2 = fminf(fmaxf(cy + hv * 0.5f, 0.f), 799.f);
    obj[e] = objv;
    *(float4*)(boxes + (size_t)e * 4) = make_float4(x1, y1, x2, y2);
    unsigned int u = sortable_f(objv);
    atomicAdd(&hist[u >> 16], 1u);
}

// ---------------- top-1000 ----------------
__global__ __launch_bounds__(1024) void k_cutoff(const unsigned int* __restrict__ hist, unsigned int* __restrict__ cut) {
    __shared__ unsigned int S[1024];
    int t = threadIdx.x;
    int lo = 65536 - 64 * (t + 1);
    unsigned int s = 0;
    for (int b = 0; b < 64; ++b) s += hist[lo + b];
    S[t] = s;
    __syncthreads();
    for (int off = 1; off < 1024; off <<= 1) {
        unsigned int add = (t >= off) ? S[t - off] : 0u;
        __syncthreads();
        S[t] += add;
        __syncthreads();
    }
    unsigned int incl = S[t], excl = incl - s;
    if (excl < 1000u && incl >= 1000u) {
        unsigned int cum = excl;
        int bin = 65536 - 64 * t - 1;
        unsigned int cutbin = 0;
        for (int b = 0; b < 64; ++b) {
            cum += hist[bin - b];
            if (cum >= 1000u) { cutbin = (unsigned int)(bin - b); break; }
        }
        cut[0] = cutbin;
    }
}

__global__ __launch_bounds__(256) void k_compact(const float* __restrict__ obj, const unsigned int* __restrict__ cut,
                                                 unsigned int* __restrict__ cnt, unsigned long long* __restrict__ cand) {
    int e = blockIdx.x * 256 + threadIdx.x;
    if (e >= NANCH) return;
    unsigned int u = sortable_f(obj[e]);
    if ((u >> 16) >= cut[0]) {
        unsigned int pos = atomicAdd(cnt, 1u);
        if (pos < 4096u) cand[pos] = (((unsigned long long)u) << 32) | (unsigned int)(~e);
    }
}

__global__ __launch_bounds__(1024) void k_sort(const unsigned int* __restrict__ cnt, const unsigned long long* __restrict__ cand,
                                               const float* __restrict__ obj, const float* __restrict__ boxes,
                                               float* __restrict__ tops, float* __restrict__ topb) {
    __shared__ unsigned long long sd[4096];
    int t = threadIdx.x;
    int n = (int)cnt[0]; if (n > 4096) n = 4096;
    int sz = (n <= 2048) ? 2048 : 4096;
    for (int i = t; i < sz; i += 1024) sd[i] = (i < n) ? cand[i] : 0ULL;
    __syncthreads();
    for (int k = 2; k <= sz; k <<= 1)
        for (int j = k >> 1; j > 0; j >>= 1) {
            for (int q = t; q < (sz >> 1); q += 1024) {
                int i = 2 * q - (q & (j - 1));
                int ix = i | j;
                unsigned long long a = sd[i], b = sd[ix];
                bool desc = ((i & k) == 0);
                if (desc ? (a < b) : (a > b)) { sd[i] = b; sd[ix] = a; }
            }
            __syncthreads();
        }
    if (t < PRE) {
        unsigned long long key = sd[t];
        unsigned int idx = ~(unsigned int)(key & 0xFFFFFFFFULL);
        tops[t] = obj[idx];
        *(float4*)(topb + (size_t)t * 4) = *(const float4*)(boxes + (size_t)idx * 4);
    }
}

// ---------------- NMS: IoU bitmask + single-wave walk ----------------
__global__ __launch_bounds__(1024) void k_ioumask(const float* __restrict__ topb,
                                                  unsigned long long* __restrict__ iomask) {
    int i = blockIdx.x;
    int j = threadIdx.x;
    float4 bi = *(const float4*)(topb + (size_t)i * 4);
    float areai = (bi.z - bi.x) * (bi.w - bi.y);
    bool sup = false;
    if (j < PRE) {
        float4 bj = *(const float4*)(topb + (size_t)j * 4);
        float areaj = (bj.z - bj.x) * (bj.w - bj.y);
        float ltx = fmaxf(bi.x, bj.x), lty = fmaxf(bi.y, bj.y);
        float rbx = fminf(bi.z, bj.z), rby = fminf(bi.w, bj.w);
        float iw = fmaxf(rbx - ltx, 0.f), ih = fmaxf(rby - lty, 0.f);
        float inter = iw * ih;
        float iou = inter / (areai + areaj - inter + 1e-6f);
        sup = iou > NMS_T;
    }
    unsigned long long m = __ballot(sup);
    if ((j & 63) == 0) iomask[(size_t)i * 16 + (j >> 6)] = m;
}

__global__ __launch_bounds__(64) void k_nmswalk(const unsigned long long* __restrict__ iomask,
                                                const float* __restrict__ topb,
                                                int* __restrict__ keep, int* __restrict__ validi, float* __restrict__ validf,
                                                float* __restrict__ rois, float* __restrict__ outRois) {
    int lane = threadIdx.x;
    __shared__ int keepL[POST];
    __shared__ int valL[POST];
    unsigned long long aw = 0ULL;
    if (lane < 16) aw = (lane == 15) ? 0x000000FFFFFFFFFFULL : ~0ULL;
    for (int it = 0; it < POST; ++it) {
        unsigned long long nz = __ballot(aw != 0ULL);
        int s, ok;
        if (nz == 0ULL) { s = 0; ok = 0; }
        else {
            int fl = __ffsll((unsigned long long)nz) - 1;
            unsigned long long w0 = __shfl(aw, fl, 64);
            int bit = __ffsll(w0) - 1;
            s = fl * 64 + bit; ok = 1;
        }
        if (lane == 0) { keepL[it] = s; valL[it] = ok; }
        if (lane < 16) {
            if (!ok) aw = 0ULL;
            else aw &= ~iomask[(size_t)s * 16 + lane];
        }
    }
    __syncthreads();
    for (int i = lane; i < POST; i += 64) {
        int kk = keepL[i]; int ok = valL[i];
        float vf = ok ? 1.f : 0.f;
        keep[i] = kk; validi[i] = ok; validf[i] = vf;
        float4 b = *(const float4*)(topb + (size_t)kk * 4);
        float4 r4 = make_float4(b.x * vf, b.y * vf, b.z * vf, b.w * vf);
        *(float4*)(rois + (size_t)i * 4) = r4;
        *(float4*)(outRois + (size_t)i * 4) = r4;
    }
}

// ---------------- RoIAlign from split planes ----------------
// OUTM 0: fp32 ; 2: hi-plane only
template<int P, int OUTM>
__global__ __launch_bounds__(256) void k_roialign(const u16* __restrict__ fh, const u16* __restrict__ fl,
                                                  const float* __restrict__ rois,
                                                  float* __restrict__ outF, u16* __restrict__ oh) {
    const int S = 2 * P;
    int b = blockIdx.x;
    int pyx = blockIdx.y;
    int py = pyx / P, px = pyx - py * P;
    int c = threadIdx.x;
    const float* r = rois + (size_t)b * 4;
    float x1 = r[0] * 0.25f, y1 = r[1] * 0.25f, x2 = r[2] * 0.25f, y2 = r[3] * 0.25f;
    float h = fmaxf(y2 - y1, 1.f), w = fmaxf(x2 - x1, 1.f);
    float acc = 0.f;
    for (int sy = 2 * py; sy < 2 * py + 2; ++sy)
        for (int sx = 2 * px; sx < 2 * px + 2; ++sx) {
            float ys = y1 + (sy + 0.5f) * (h / (float)S);
            float xs = x1 + (sx + 0.5f) * (w / (float)S);
            float y0f = floorf(ys), x0f = floorf(xs);
            float ly = ys - y0f, lx = xs - x0f;
            int y0 = min(max((int)y0f, 0), FH - 1);
            int y1i = min(max((int)y0f + 1, 0), FH - 1);
            int x0 = min(max((int)x0f, 0), FW - 1);
            int x1i = min(max((int)x0f + 1, 0), FW - 1);
            size_t i00 = ((size_t)(y0 * FW + x0)) * 256 + c;
            size_t i01 = ((size_t)(y0 * FW + x1i)) * 256 + c;
            size_t i10 = ((size_t)(y1i * FW + x0)) * 256 + c;
            size_t i11 = ((size_t)(y1i * FW + x1i)) * 256 + c;
            float f00 = bff(fh[i00]) + bff(fl[i00]);
            float f01 = bff(fh[i01]) + bff(fl[i01]);
            float f10 = bff(fh[i10]) + bff(fl[i10]);
            float f11 = bff(fh[i11]) + bff(fl[i11]);
            acc += f00 * (1.f - ly) * (1.f - lx) + f01 * (1.f - ly) * lx + f10 * ly * (1.f - lx) + f11 * ly * lx;
        }
    float v = acc * 0.25f;
    size_t oi = ((size_t)((b * P + py) * P + px)) * 256 + c;
    if constexpr (OUTM == 0) outF[oi] = v;
    else oh[oi] = bf16r(v);
}

// ---------------- softmax + scores + labels ----------------
__global__ __launch_bounds__(64) void k_softmax(const float* __restrict__ logits, const int* __restrict__ validi,
                                                const float* __restrict__ validf, int* __restrict__ labOut,
                                                float* __restrict__ dout) {
    int b = blockIdx.x, t = threadIdx.x;
    const float* L = logits + (size_t)b * 128;
    float l0 = (t < 81) ? L[t] : -INFINITY;
    float l1 = (t + 64 < 81) ? L[t + 64] : -INFINITY;
    float mx = fmaxf(l0, l1);
    for (int off = 32; off > 0; off >>= 1) mx = fmaxf(mx, __shfl_xor(mx, off, 64));
    float e0 = expf(l0 - mx), e1 = expf(l1 - mx);
    float sum = e0 + e1;
    for (int off = 32; off > 0; off >>= 1) sum += __shfl_xor(sum, off, 64);
    float fv = (t >= 1 && t < 81) ? l0 : -INFINITY;
    int fi = t;
    float fv2 = (t + 64 < 81) ? l1 : -INFINITY;
    if (fv2 > fv || (fv2 == fv && (t + 64) < fi)) { fv = fv2; fi = t + 64; }
    for (int off = 32; off > 0; off >>= 1) {
        float ov = __shfl_xor(fv, off, 64);
        int oi = __shfl_xor(fi, off, 64);
        if (ov > fv || (ov == fv && oi < fi)) { fv = ov; fi = oi; }
    }
    if (t == 0) {
        float prob = expf(fv - mx) / sum;
        int vi = validi[b];
        labOut[b] = fi * vi;
        dout[OUT_LABS + b] = (float)(fi * vi);
        dout[OUT_SC + b] = prob * validf[b];
    }
}

// ---------------- final masks ----------------
__global__ __launch_bounds__(256) void k_masks(const float* __restrict__ dpart, const float* __restrict__ validf,
                                               float* __restrict__ dout) {
    int e = blockIdx.x * 256 + threadIdx.x;
    if (e >= 100 * 28 * 28) return;
    int b = e / 784; int r = e - b * 784;
    int y = r / 28, x = r - y * 28;
    int pyx = (y & 1) * 2 + (x & 1);
    int m = (b * 14 + (y >> 1)) * 14 + (x >> 1);
    float s = dpart[(size_t)(pyx * 2 + 0) * 19600 + m] + dpart[(size_t)(pyx * 2 + 1) * 19600 + m];
    float val = 1.f / (1.f + expf(-s)) * validf[b];
    dout[OUT_MASK + (size_t)b * 784 + y * 28 + x] = val;
}

// ---------------- host ----------------
extern "C" void kernel_launch(void* const* d_in, const int* in_sizes, int n_in,
                              void* d_out, int out_size, void* d_ws, size_t ws_size,
                              hipStream_t stream) {
    const float* image = (const float*)d_in[0];
    const float* stem_w1 = (const float*)d_in[1];
    const float* stem_w2 = (const float*)d_in[2];
    const float* rpn_w = (const float*)d_in[3];
    const float* rpn_cls_w = (const float*)d_in[4];
    const float* rpn_box_w = (const float*)d_in[5];
    const float* fc1_w = (const float*)d_in[6];
    const float* fc2_w = (const float*)d_in[7];
    const float* cls_w = (const float*)d_in[8];
    const float* mask_w1 = (const float*)d_in[9];
    const float* mask_w2 = (const float*)d_in[10];
    const float* mask_w3 = (const float*)d_in[11];
    const float* mask_w4 = (const float*)d_in[12];
    const float* mask_deconv_w = (const float*)d_in[13];
    const float* mask_pred_w = (const float*)d_in[14];
    char* ws = (char*)d_ws;
    float* out = (float*)d_out;

    auto F = [&](size_t b) { return (float*)(ws + b); };
    auto U = [&](size_t b) { return (u16*)(ws + b); };

    unsigned int* cnt = (unsigned int*)(ws + B_CNT);
    unsigned int* cut = (unsigned int*)(ws + B_CUT);
    unsigned int* hist = (unsigned int*)(ws + B_HIST);
    unsigned int* zbuf32 = (unsigned int*)(ws + B_ZBUF);
    const u16* zb = (const u16*)(ws + B_ZBUF);
    unsigned long long* cand = (unsigned long long*)(ws + B_POOL);               // dead before POOL written
    unsigned long long* iomask = (unsigned long long*)(ws + B_POOL + 32768);     // dead before POOL written
    int* keep = (int*)(ws + B_KEEP);
    int* validi = (int*)(ws + B_VALI);
    int* labels = (int*)(ws + B_LAB);

    // all init + weight packing in one launch
    k_packs<<<37628, 256, 0, stream>>>(
        image, stem_w1, stem_w2, rpn_w, rpn_cls_w, rpn_box_w, fc1_w, fc2_w, cls_w,
        mask_w1, mask_w2, mask_w3, mask_w4, mask_deconv_w,
        hist, cnt, zbuf32,
        F(B_WFC2), F(B_WCLS), F(B_WFC1),
        U(B_WSP_S2), U(B_WSP_RPN), U(B_WSP_M1), U(B_WSP_DC), U(B_WRPNH), U(B_WS1),
        U(B_IMGH), U(B_IMGL));

    // backbone (16x16x32 MFMA, r3 structure)
    k_mfma<2, 0, 1, 1, 3><<<dim3(1, 475), 256, 0, stream>>>(
        U(B_IMGH), U(B_IMGL), U(B_WS1), nullptr, U(B_S1H), U(B_S1L), 64, 64,
        FHW, FH, FW, 2, 7, 0, zb, nullptr, nullptr, nullptr, 0);
    k_mfma<1, 0, 1, 1, 3><<<dim3(2, 475), 256, 0, stream>>>(
        U(B_S1H), U(B_S1L), U(B_WSP_S2), nullptr, U(B_FEATH), U(B_FEATL), 256, 256,
        FHW, FH, FW, 6, 18, 0, zb, nullptr, nullptr, nullptr, 0);
    k_mfma<1, 0, 1, 1, 3><<<dim3(2, 475), 256, 0, stream>>>(
        U(B_FEATH), U(B_FEATL), U(B_WSP_RPN), nullptr, U(B_TH), U(B_TL), 256, 256,
        FHW, FH, FW, 8, 72, 0, zb, nullptr, nullptr, nullptr, 0);
    k_rpnhead<<<238, 256, 0, stream>>>(U(B_TH), U(B_TL), rpn_cls_w, rpn_box_w, F(B_RPNO));

    // proposals
    k_decodehist<<<713, 256, 0, stream>>>(F(B_RPNO), F(B_OBJ), F(B_BOX), hist);
    k_cutoff<<<1, 1024, 0, stream>>>(hist, cut);
    k_compact<<<713, 256, 0, stream>>>(F(B_OBJ), cut, cnt, cand);
    k_sort<<<1, 1024, 0, stream>>>(cnt, cand, F(B_OBJ), F(B_BOX), F(B_TOPS), F(B_TOPB));
    k_ioumask<<<PRE, 1024, 0, stream>>>(F(B_TOPB), iomask);
    k_nmswalk<<<1, 64, 0, stream>>>(iomask, F(B_TOPB), keep, validi, F(B_VALF), F(B_ROIS), out + OUT_ROIS);

    // box head
    k_roialign<7, 0><<<dim3(100, 49), 256, 0, stream>>>(U(B_FEATH), U(B_FEATL), F(B_ROIS), F(B_POOL), nullptr);
    k_gemm<1, 0><<<dim3(8, 1, 28), 256, 0, stream>>>(F(B_POOL), F(B_WFC1), F(B_PART), 1024, 1024,
        100, 1024, 28, 12544);
    k_reduce<<<400, 256, 0, stream>>>(F(B_PART), F(B_X1), 100, 1024, 28, 1);
    k_gemm<1, 0><<<dim3(8, 1, 8), 256, 0, stream>>>(F(B_X1), F(B_WFC2), F(B_PART), 1024, 1024,
        100, 1024, 8, 1024);
    k_reduce<<<400, 256, 0, stream>>>(F(B_PART), F(B_X2), 100, 1024, 8, 1);
    k_gemm<1, 0><<<dim3(1, 1, 8), 256, 0, stream>>>(F(B_X2), F(B_WCLS), F(B_PART), 128, 128,
        100, 128, 8, 1024);
    k_reduce<<<50, 256, 0, stream>>>(F(B_PART), F(B_LOG), 100, 128, 8, 0);
    k_softmax<<<100, 64, 0, stream>>>(F(B_LOG), validi, F(B_VALF), labels, out);

    // mask head (convs 2-term; deconv 2-term)
    k_roialign<14, 2><<<dim3(100, 196), 256, 0, stream>>>(U(B_FEATH), U(B_FEATL), F(B_ROIS), nullptr, U(B_M0H));
    k_mfma<1, 0, 1, 3, 2><<<dim3(2, 154), 256, 0, stream>>>(
        U(B_M0H), nullptr, U(B_WSP_M1), nullptr, U(B_MP1H), nullptr, 256, 256,
        19600, 14, 14, 8, 72, 0, zb, nullptr, nullptr, nullptr, 0);
    k_mfma<1, 0, 1, 3, 2><<<dim3(2, 154), 256, 0, stream>>>(
        U(B_MP1H), nullptr, U(B_WSP_M1) + 1179648, nullptr, U(B_MP2H), nullptr, 256, 256,
        19600, 14, 14, 8, 72, 0, zb, nullptr, nullptr, nullptr, 0);
    k_mfma<1, 0, 1, 3, 2><<<dim3(2, 154), 256, 0, stream>>>(
        U(B_MP2H), nullptr, U(B_WSP_M1) + 2 * 1179648, nullptr, U(B_MP1H), nullptr, 256, 256,
        19600, 14, 14, 8, 72, 0, zb, nullptr, nullptr, nullptr, 0);
    k_mfma<1, 0, 1, 3, 2><<<dim3(2, 154), 256, 0, stream>>>(
        U(B_MP1H), nullptr, U(B_WSP_M1) + 3 * 1179648, nullptr, U(B_MP2H), nullptr, 256, 256,
        19600, 14, 14, 8, 72, 0, zb, nullptr, nullptr, nullptr, 0);
    k_mfma<0, 2, 0, 0, 2><<<dim3(8, 154), 256, 0, stream>>>(
        U(B_MP2H), nullptr, U(B_WSP_DC), nullptr, nullptr, nullptr, 0, 0,
        19600, 0, 0, 8, 8, 256, zb, labels, mask_pred_w, F(B_DP), 19600);
    k_masks<<<307, 256, 0, stream>>>(F(B_DP), F(B_VALF), out);

    (void)in_sizes; (void)n_in; (void)out_size; (void)ws_size;
}

// Round 8
// 922.053 us; speedup vs baseline: 1.1113x; 1.1113x over previous
//
#include <hip/hip_runtime.h>
#include <cstdint>
#include <cstddef>

constexpr int IMG_H = 800, IMG_W = 1216;
constexpr int FH = 200, FW = 304;
constexpr int FHW = FH * FW;            // 60800
constexpr int NANCH = 3 * FHW;          // 182400
constexpr int PRE = 1000, POST = 100;
constexpr float NMS_T = 0.7f;
constexpr int QH = 803, QW = 1220;      // padded split image dims (c4 inner)

// ---------------- workspace layout (BYTE offsets) ----------------
constexpr size_t B_FEATH = 0;                       // bf16 60800*256
constexpr size_t B_FEATL = 31129600;                // bf16
constexpr size_t B_T     = 62259200;                // overlay region
constexpr size_t B_S1H   = B_T;                     // stem1 hi plane 60800*64*2
constexpr size_t B_S1L   = B_T + 7782400;
constexpr size_t B_TH    = B_T;                     // rpn t hi plane 60800*256*2
constexpr size_t B_TL    = B_T + 31129600;          // rpn t lo plane
constexpr size_t B_PART  = B_T;                     // fp32 28*128*1024 (box head)
constexpr size_t B_M0H   = B_T;                     // mask hi planes 19600*256*2 each
constexpr size_t B_MP1H  = B_T + 10035200;
constexpr size_t B_MP2H  = B_T + 20070400;
constexpr size_t B_DP    = B_T + 30105600;          // fp32 8*19600
constexpr size_t B_RPNO  = 124518400;               // fp32 60800*16
constexpr size_t B_OBJ   = 128409600;               // fp32 182400
constexpr size_t B_BOX   = 129139200;               // fp32 182400*4
constexpr size_t B_HIST  = 132057600;               // u32 65536
constexpr size_t B_MISC  = 132319744;               // 64KB misc
constexpr size_t B_POOL  = 132385280;               // fp32 100*49*256 (cand + iomask overlay early)
constexpr size_t B_X1    = 137402880;               // fp32 100*1024
constexpr size_t B_X2    = 137812480;
constexpr size_t B_LOG   = 138222080;               // fp32 100*128
constexpr size_t B_WRPNH = 138273280;               // u16 split rpn-head weights (unused now, kept)
constexpr size_t B_WFC2  = 138404352;               // fp32 1024*1024
constexpr size_t B_WCLS  = 142598656;               // fp32 1024*128
constexpr size_t B_WFC1  = 143122944;               // fp32 12544*1024
constexpr size_t B_WSP   = 194503168;               // split weights (bf16)
constexpr size_t B_WSP_S2  = B_WSP;                 // 576*256*4
constexpr size_t B_WSP_RPN = B_WSP_S2 + 589824;     // 2304*256*4
constexpr size_t B_WSP_M1  = B_WSP_RPN + 2359296;   // 4x 1179648
constexpr size_t B_WSP_DC  = B_WSP_M1 + 4 * 1179648;
constexpr size_t B_IMGH  = B_WSP_DC + 1048576;
constexpr size_t B_IMGL  = B_IMGH + 7837280;
constexpr size_t B_WS1   = B_IMGL + 7837280;        // stem1 split weights 114688 B
// MISC sublayout
constexpr size_t B_CNT  = B_MISC + 0;
constexpr size_t B_CUT  = B_MISC + 4;
constexpr size_t B_ZBUF = B_MISC + 256;             // 256B zeros
constexpr size_t B_TOPS = B_MISC + 512;             // 1000 f
constexpr size_t B_TOPB = B_MISC + 4608;            // 4000 f
constexpr size_t B_KEEP = B_MISC + 20608;           // 100 i
constexpr size_t B_VALI = B_MISC + 21008;
constexpr size_t B_VALF = B_MISC + 21408;
constexpr size_t B_ROIS = B_MISC + 21808;           // 400 f
constexpr size_t B_LAB  = B_MISC + 23408;           // 100 i
// d_out offsets (floats)
constexpr size_t OUT_ROIS = 0, OUT_LABS = 400, OUT_MASK = 500, OUT_SC = 78900;

using f32x4 = __attribute__((ext_vector_type(4))) float;
using s16x8 = __attribute__((ext_vector_type(8))) short;
typedef unsigned short u16;

__device__ __forceinline__ u16 bf16r(float f) {
    unsigned u = __float_as_uint(f);
    return (u16)((u + 0x7FFFu + ((u >> 16) & 1u)) >> 16);
}
__device__ __forceinline__ float bff(u16 h) { return __uint_as_float(((unsigned)h) << 16); }

__device__ __forceinline__ unsigned int sortable_f(float f) {
    unsigned int u = __float_as_uint(f);
    return (u & 0x80000000u) ? ~u : (u | 0x80000000u);
}

// conv3x3 split pack helper
__device__ __forceinline__ void packsplit3_body(int e, const float* __restrict__ w, u16* __restrict__ dst,
                                                int C, int clog2, int nks) {
    int j = e & 7, col = (e >> 3) & 127, kblk = (e >> 10) & 3;
    int g = e >> 12; int ks = g % nks; int nt = g / nks;
    int k = ks * 32 + kblk * 8 + j;
    int o = nt * 128 + col;
    int c = k & (C - 1); int q = k >> clog2;
    int ky = q / 3, kx = q - ky * 3;
    float v = w[(size_t)(o * C + c) * 9 + ky * 3 + kx];
    u16 h = bf16r(v); u16 l = bf16r(v - bff(h));
    size_t base = (size_t)(nt * nks + ks) * 8192 + kblk * 1024 + col * 8 + j;
    dst[base] = h; dst[base + 4096] = l;
}

// ---------------- ALL init + weight packing in ONE kernel ----------------
__global__ __launch_bounds__(256) void k_packs(
    const float* __restrict__ image, const float* __restrict__ stem_w1, const float* __restrict__ stem_w2,
    const float* __restrict__ rpn_w, const float* __restrict__ rpn_cls_w, const float* __restrict__ rpn_box_w,
    const float* __restrict__ fc1_w, const float* __restrict__ fc2_w, const float* __restrict__ cls_w,
    const float* __restrict__ mw0, const float* __restrict__ mw1, const float* __restrict__ mw2,
    const float* __restrict__ mw3, const float* __restrict__ wd,
    unsigned int* __restrict__ hist, unsigned int* __restrict__ cnt, unsigned int* __restrict__ zbuf,
    float* __restrict__ wfc2, float* __restrict__ wcls, float* __restrict__ wfc1,
    u16* __restrict__ wsp_s2, u16* __restrict__ wsp_rpn, u16* __restrict__ wsp_m, u16* __restrict__ wsp_dc,
    u16* __restrict__ wrpnh, u16* __restrict__ ws1, u16* __restrict__ imgh, u16* __restrict__ imgl)
{
    __shared__ float tile[64][50];
    int b = blockIdx.x, t = threadIdx.x;
    if (b < 256) {
        int i = b * 256 + t;
        if (i < 65536) hist[i] = 0u;
        if (i < 64) zbuf[i] = 0u;
        if (i == 0) cnt[0] = 0u;
    } else if (b < 4352) {          // fc2^T
        int e = (b - 256) * 256 + t;
        int k = e >> 10, n = e & 1023;
        wfc2[e] = fc2_w[(size_t)n * 1024 + k];
    } else if (b < 4864) {          // cls^T pad 128
        int e = (b - 4352) * 256 + t;
        int k = e >> 7, n = e & 127;
        wcls[e] = (n < 81) ? cls_w[(size_t)n * 1024 + k] : 0.f;
    } else if (b < 8960) {          // fc1 transpose
        int bb = b - 4864;
        int c = bb >> 4, n0 = (bb & 15) * 64;
        for (int e = t; e < 64 * 49; e += 256) {
            int nn = e / 49, ss = e - nn * 49;
            tile[nn][ss] = fc1_w[(size_t)(n0 + nn) * 12544 + c * 49 + ss];
        }
        __syncthreads();
        for (int e = t; e < 49 * 64; e += 256) {
            int ss = e >> 6, nn = e & 63;
            wfc1[(size_t)(ss * 256 + c) * 1024 + n0 + nn] = tile[nn][ss];
        }
    } else if (b < 9536) {          // stem2 split
        packsplit3_body((b - 8960) * 256 + t, stem_w2, wsp_s2, 64, 6, 18);
    } else if (b < 11840) {         // rpn split
        packsplit3_body((b - 9536) * 256 + t, rpn_w, wsp_rpn, 256, 8, 72);
    } else if (b < 21056) {         // mask convs x4
        int bb = b - 11840;
        int z = bb / 2304;
        const float* w = (z == 0) ? mw0 : (z == 1) ? mw1 : (z == 2) ? mw2 : mw3;
        packsplit3_body((bb - z * 2304) * 256 + t, w, wsp_m + (size_t)z * 1179648, 256, 8, 72);
    } else if (b < 22080) {         // deconv fused
        int e = (b - 21056) * 256 + t;
        int j = e & 7, col = (e >> 3) & 127, kblk = (e >> 10) & 3;
        int g = e >> 12; int ks = g & 7; int nt = g >> 3;
        int k = ks * 32 + kblk * 8 + j;
        int n = nt * 128 + col;
        int pyx = n >> 8, o = n & 255;
        int py = pyx >> 1, px = pyx & 1;
        float v = wd[(size_t)(o * 256 + k) * 4 + (1 - py) * 2 + (1 - px)];
        u16 h = bf16r(v); u16 l = bf16r(v - bff(h));
        size_t base = (size_t)(nt * 8 + ks) * 8192 + kblk * 1024 + col * 8 + j;
        wsp_dc[base] = h; wsp_dc[base + 4096] = l;
    } else if (b < 22208) {         // rpn head split (unused, kept for range stability)
        int e = (b - 22080) * 256 + t;
        int j = e & 7, col = (e >> 3) & 127, kblk = (e >> 10) & 3, ks = e >> 12;
        int k = ks * 32 + kblk * 8 + j;
        float v = 0.f;
        if (col < 3) v = rpn_cls_w[col * 256 + k];
        else if (col < 15) v = rpn_box_w[(col - 3) * 256 + k];
        u16 h = bf16r(v); u16 l = bf16r(v - bff(h));
        size_t base = (size_t)ks * 8192 + kblk * 1024 + col * 8 + j;
        wrpnh[base] = h; wrpnh[base + 4096] = l;
    } else if (b < 22320) {         // stem1 weights split
        int e = (b - 22208) * 256 + t;
        int j = e & 7, col = (e >> 3) & 127, kblk = (e >> 10) & 3, ks = e >> 12;
        int k = ks * 32 + kblk * 8 + j;
        int ky = k >> 5, kx = (k >> 2) & 7, c = k & 3;
        float v = 0.f;
        if (kx < 7 && c < 3 && col < 64) v = stem_w1[(((size_t)col * 3 + c) * 7 + ky) * 7 + kx];
        u16 h = bf16r(v); u16 l = bf16r(v - bff(h));
        size_t base = (size_t)ks * 8192 + kblk * 1024 + col * 8 + j;
        ws1[base] = h; ws1[base + 4096] = l;
    } else {                        // padded image split
        int e = (b - 22320) * 256 + t;
        if (e < QH * QW * 4) {
            int c = e & 3; int p = e >> 2;
            int xx = p % QW; int yy = p / QW;
            int iy = yy - 1, ix = xx - 1;
            float v = 0.f;
            if (c < 3 && (unsigned)iy < (unsigned)IMG_H && (unsigned)ix < (unsigned)IMG_W)
                v = image[((size_t)c * IMG_H + iy) * IMG_W + ix];
            u16 h = bf16r(v);
            imgh[e] = h; imgl[e] = bf16r(v - bff(h));
        }
    }
}

// ---------------- split-bf16 MFMA GEMM (implicit conv), 16x16x32 inner (r3 structure) ----------------
// A,B staged via LDS, single-buffered, 2 barriers per K-step — measured-best structure.
// AMODE 0: flat A rows (stride Kflat); 1: 3x3 SAME im2col HWC (C=1<<clog2); 2: stem1 7x7 s4
// TERMS 3: ah*bh+ah*bl+al*bh ; 2: ah*bh+ah*bl ; 1: ah*bh
// OUTK: 0 fp32, 1 split hi+lo, 3 hi only  (all guard n<nstore)
// EPI 0: store; EPI 2: fused deconv mask-pred partial
template<int AMODE, int EPI, int RELU, int OUTK, int TERMS>
__global__ __launch_bounds__(256) void k_mfma(
    const u16* __restrict__ Ahi, const u16* __restrict__ Alo,
    const u16* __restrict__ Bsp,
    float* __restrict__ outF, u16* __restrict__ outH, u16* __restrict__ outL,
    int ostride, int nstore,
    int M, int H, int W, int clog2, int nks, int Kflat,
    const u16* __restrict__ zb,
    const int* __restrict__ labels, const float* __restrict__ wp,
    float* __restrict__ dpart, int Mtot)
{
    constexpr int APL = (TERMS == 3) ? 8192 : 4096;
    constexpr int BPL = (TERMS >= 2) ? 8192 : 4096;
    __shared__ u16 Al[APL];
    __shared__ u16 Bl[BPL];
    __shared__ float scr[2][128];
    const int tid = threadIdx.x;
    // XCD-contiguous bijective swizzle (m204)
    int lin = blockIdx.y * gridDim.x + blockIdx.x;
    int nb = gridDim.x * gridDim.y;
    int qq = nb >> 3, rr = nb & 7;
    int xcd = lin & 7, rkk = lin >> 3;
    int nlin = (xcd < rr ? xcd * (qq + 1) : rr * (qq + 1) + (xcd - rr) * qq) + rkk;
    const int nt = nlin % gridDim.x, mt = nlin / gridDim.x;

    const int m0 = mt * 128, n0 = nt * 128;
    const int w = tid >> 6, lane = tid & 63;
    const int wr = w >> 1, wc = w & 1;
    const int lhi = lane >> 4, llo = lane & 15;

    const int row = tid & 127;
    const int kb0 = tid >> 7;     // 0 or 1
    const int m = m0 + row;
    const bool mv = (m < M);
    int pbase = 0, pi = 0, pj = 0;
    if (AMODE >= 1) {
        int mm = mv ? m : 0;
        int HW = H * W;
        int b = mm / HW; int r2 = mm - b * HW;
        pi = r2 / W; pj = r2 - pi * W;
        pbase = b * HW;
    }

    f32x4 acc[4][4];
#pragma unroll
    for (int i = 0; i < 4; ++i)
#pragma unroll
        for (int j = 0; j < 4; ++j) acc[i][j] = (f32x4)(0.f);

    int4 rA0, rA1, rA2, rA3, rB0, rB1, rB2, rB3;

    auto loadA = [&](int ks) {
        const u16 *sh, *sl = nullptr;
        if (AMODE == 1) {
            int k0 = ks * 32; int q = k0 >> clog2; int c0 = k0 & ((1 << clog2) - 1);
            int ky = q / 3, kx = q - ky * 3;
            int yy = pi + ky - 1, xx = pj + kx - 1;
            bool ok = mv && (unsigned)yy < (unsigned)H && (unsigned)xx < (unsigned)W;
            size_t off = (((size_t)(pbase + yy * W + xx)) << clog2) + c0 + kb0 * 8;
            sh = ok ? Ahi + off : zb;
            if (TERMS == 3) sl = ok ? Alo + off : zb;
        } else if (AMODE == 2) {
            int kk = ks * 32 + kb0 * 8;
            int ky = kk >> 5;
            int kx0 = (kk >> 2) & 7;
            size_t off = ((size_t)(pi * 4 + ky) * QW + pj * 4 + kx0) * 4;
            sh = Ahi + off;
            if (TERMS == 3) sl = Alo + off;
        } else {
            size_t off = (size_t)(mv ? m : 0) * Kflat + ks * 32 + kb0 * 8;
            sh = mv ? Ahi + off : zb;
            if (TERMS == 3) sl = mv ? Alo + off : zb;
        }
        rA0 = *(const int4*)sh;  rA1 = *(const int4*)(sh + 16);
        if (TERMS == 3) { rA2 = *(const int4*)sl;  rA3 = *(const int4*)(sl + 16); }
    };
    auto loadB = [&](int ks) {
        const u16* bs = Bsp + ((size_t)(nt * nks + ks)) * 8192;
        rB0 = *(const int4*)(bs + (size_t)tid * 8);
        rB1 = *(const int4*)(bs + (size_t)(tid + 256) * 8);
        if (TERMS >= 2) {
            rB2 = *(const int4*)(bs + (size_t)(tid + 512) * 8);
            rB3 = *(const int4*)(bs + (size_t)(tid + 768) * 8);
        }
    };
    auto stash = [&]() {
        *(int4*)&Al[(size_t)((kb0    ) * 128 + row) * 8] = rA0;
        *(int4*)&Al[(size_t)((kb0 + 2) * 128 + row) * 8] = rA1;
        if (TERMS == 3) {
            *(int4*)&Al[4096 + (size_t)((kb0    ) * 128 + row) * 8] = rA2;
            *(int4*)&Al[4096 + (size_t)((kb0 + 2) * 128 + row) * 8] = rA3;
        }
        *(int4*)&Bl[(size_t)tid * 8] = rB0;
        *(int4*)&Bl[(size_t)(tid + 256) * 8] = rB1;
        if (TERMS >= 2) {
            *(int4*)&Bl[(size_t)(tid + 512) * 8] = rB2;
            *(int4*)&Bl[(size_t)(tid + 768) * 8] = rB3;
        }
    };

    loadA(0); loadB(0);
    for (int ks = 0; ks < nks; ++ks) {
        if (ks) __syncthreads();
        stash();
        __syncthreads();
        if (ks + 1 < nks) { loadA(ks + 1); loadB(ks + 1); }
        s16x8 fAh[4], fAl2[4], fBh[4], fBl[4];
#pragma unroll
        for (int i = 0; i < 4; ++i) {
            int ar = wr * 64 + i * 16 + llo;
            fAh[i]  = *(const s16x8*)&Al[(size_t)(lhi * 128 + ar) * 8];
            if (TERMS == 3) fAl2[i] = *(const s16x8*)&Al[4096 + (size_t)(lhi * 128 + ar) * 8];
            int bc = wc * 64 + i * 16 + llo;
            fBh[i] = *(const s16x8*)&Bl[(size_t)(lhi * 128 + bc) * 8];
            if (TERMS >= 2) fBl[i] = *(const s16x8*)&Bl[4096 + (size_t)(lhi * 128 + bc) * 8];
        }
#pragma unroll
        for (int i = 0; i < 4; ++i)
#pragma unroll
            for (int j = 0; j < 4; ++j) {
                acc[i][j] = __builtin_amdgcn_mfma_f32_16x16x32_bf16(fAh[i],  fBh[j], acc[i][j], 0, 0, 0);
                if (TERMS >= 2)
                    acc[i][j] = __builtin_amdgcn_mfma_f32_16x16x32_bf16(fAh[i],  fBl[j], acc[i][j], 0, 0, 0);
                if (TERMS == 3)
                    acc[i][j] = __builtin_amdgcn_mfma_f32_16x16x32_bf16(fAl2[i], fBh[j], acc[i][j], 0, 0, 0);
            }
    }

    if (EPI == 0) {
#pragma unroll
        for (int i = 0; i < 4; ++i)
#pragma unroll
            for (int j = 0; j < 4; ++j) {
                f32x4 v = acc[i][j];
                int n = n0 + wc * 64 + j * 16 + llo;
                if (n >= nstore) continue;
#pragma unroll
                for (int r = 0; r < 4; ++r) {
                    int mm = m0 + wr * 64 + i * 16 + lhi * 4 + r;
                    if (mm < M) {
                        float val = RELU ? fmaxf(v[r], 0.f) : v[r];
                        if constexpr (OUTK == 0) {
                            outF[(size_t)mm * ostride + n] = val;
                        } else if constexpr (OUTK == 1) {
                            u16 h = bf16r(val);
                            outH[(size_t)mm * ostride + n] = h;
                            outL[(size_t)mm * ostride + n] = bf16r(val - bff(h));
                        } else {
                            outH[(size_t)mm * ostride + n] = bf16r(val);
                        }
                    }
                }
            }
    } else {
        // EPI2: deconv + per-label mask-pred dot
#pragma unroll
        for (int i = 0; i < 4; ++i) {
            int mrow = m0 + wr * 64 + i * 16 + lhi * 4;
            int b = mrow / 196; if (b > 99) b = 99;
            int lab = labels[b];
            float wv[4];
#pragma unroll
            for (int j = 0; j < 4; ++j)
                wv[j] = wp[lab * 256 + ((n0 + wc * 64 + j * 16 + llo) & 255)];
#pragma unroll
            for (int r = 0; r < 4; ++r) {
                float s = 0.f;
#pragma unroll
                for (int j = 0; j < 4; ++j) s = fmaf(fmaxf(acc[i][j][r], 0.f), wv[j], s);
                s += __shfl_xor(s, 1, 64); s += __shfl_xor(s, 2, 64);
                s += __shfl_xor(s, 4, 64); s += __shfl_xor(s, 8, 64);
                if (llo == 0) scr[wc][wr * 64 + i * 16 + lhi * 4 + r] = s;
            }
        }
        __syncthreads();
        if (tid < 128) {
            int mm = m0 + tid;
            if (mm < M) dpart[(size_t)nt * Mtot + mm] = scr[0][tid] + scr[1][tid];
        }
    }
}

// ---------------- rpn head: 1x1 conv, 15 outputs, plain VALU (full fp32 from hi+lo) ----------------
__global__ __launch_bounds__(256) void k_rpnhead(const u16* __restrict__ th, const u16* __restrict__ tl,
                                                 const float* __restrict__ wcls, const float* __restrict__ wbox,
                                                 float* __restrict__ rpno) {
    __shared__ float W[15][256];
    int t = threadIdx.x;
    for (int e = t; e < 15 * 256; e += 256) {
        int o = e >> 8, k = e & 255;
        W[o][k] = (o < 3) ? wcls[o * 256 + k] : wbox[(o - 3) * 256 + k];
    }
    __syncthreads();
    int p = blockIdx.x * 256 + t;
    if (p >= FHW) return;
    const u16* ph = th + (size_t)p * 256;
    const u16* pl = tl + (size_t)p * 256;
    float acc[15];
#pragma unroll
    for (int o = 0; o < 15; ++o) acc[o] = 0.f;
    for (int k0 = 0; k0 < 256; k0 += 8) {
        s16x8 vh = *(const s16x8*)(ph + k0);
        s16x8 vl = *(const s16x8*)(pl + k0);
        float v[8];
#pragma unroll
        for (int j = 0; j < 8; ++j) v[j] = bff((u16)vh[j]) + bff((u16)vl[j]);
#pragma unroll
        for (int o = 0; o < 15; ++o) {
            float s = acc[o];
#pragma unroll
            for (int j = 0; j < 8; ++j) s = fmaf(v[j], W[o][k0 + j], s);
            acc[o] = s;
        }
    }
    float* rp = rpno + (size_t)p * 16;
#pragma unroll
    for (int o = 0; o < 15; ++o) rp[o] = acc[o];
    rp[15] = 0.f;
}

// ---------------- generic fp32 tile GEMM (fc head, split-K) ----------------
template<int EPI, int RELU>
__global__ __launch_bounds__(256, 2) void k_gemm(
    const float* __restrict__ Ap, const float* __restrict__ Bp,
    float* __restrict__ outp, int out_stride, int Nstore,
    int M, int Npad, int ksteps, int Kflat)
{
    __shared__ float As[16][128];
    __shared__ float Bs[16][128];
    const int tid = threadIdx.x;
    const int nt = blockIdx.x, mt = blockIdx.y, kz = blockIdx.z;
    const int m0 = mt * 128, n0 = nt * 128;
    const int ty = tid >> 4, tx = tid & 15;
    const int am = tid >> 1;
    const int kl = (tid & 1) << 3;
    const int m_g = m0 + am;
    const bool mval = (m_g < M);
    const float* aRow = Ap + (size_t)(mval ? m_g : 0) * Kflat;
    float acc[8][8];
#pragma unroll
    for (int i = 0; i < 8; ++i)
#pragma unroll
        for (int j = 0; j < 8; ++j) acc[i][j] = 0.f;
    const int kbeg = kz * ksteps * 16;
    for (int s = 0; s < ksteps; ++s) {
        const int k0 = kbeg + s * 16;
        float4 v0, v1;
        const int kk = k0 + kl;
        if (mval) {
            v0 = *(const float4*)(aRow + kk);
            v1 = *(const float4*)(aRow + kk + 4);
        } else { v0 = make_float4(0.f, 0.f, 0.f, 0.f); v1 = v0; }
        As[kl + 0][am] = v0.x; As[kl + 1][am] = v0.y; As[kl + 2][am] = v0.z; As[kl + 3][am] = v0.w;
        As[kl + 4][am] = v1.x; As[kl + 5][am] = v1.y; As[kl + 6][am] = v1.z; As[kl + 7][am] = v1.w;
        {
            const float* p = Bp + (size_t)(k0 + ty) * Npad + n0 + (tx << 3);
            float4 b0 = *(const float4*)p;
            float4 b1 = *(const float4*)(p + 4);
            *(float4*)&Bs[ty][(tx << 3)] = b0;
            *(float4*)&Bs[ty][(tx << 3) + 4] = b1;
        }
        __syncthreads();
#pragma unroll
        for (int k = 0; k < 16; ++k) {
            float4 a0 = *(const float4*)&As[k][(ty << 3)];
            float4 a1 = *(const float4*)&As[k][(ty << 3) + 4];
            float4 b0 = *(const float4*)&Bs[k][(tx << 2)];
            float4 b1 = *(const float4*)&Bs[k][64 + (tx << 2)];
            float av[8] = {a0.x, a0.y, a0.z, a0.w, a1.x, a1.y, a1.z, a1.w};
            float bv[8] = {b0.x, b0.y, b0.z, b0.w, b1.x, b1.y, b1.z, b1.w};
#pragma unroll
            for (int i = 0; i < 8; ++i)
#pragma unroll
                for (int j = 0; j < 8; ++j)
                    acc[i][j] = fmaf(av[i], bv[j], acc[i][j]);
        }
        __syncthreads();
    }
#pragma unroll
    for (int i = 0; i < 8; ++i) {
        int ml = (ty << 3) + i;
        int mm = (EPI == 1) ? (kz * 128 + ml) : (m0 + ml);
        bool mok = (EPI == 1) ? true : (mm < M);
        if (!mok) continue;
        float4 v0 = make_float4(acc[i][0], acc[i][1], acc[i][2], acc[i][3]);
        float4 v1 = make_float4(acc[i][4], acc[i][5], acc[i][6], acc[i][7]);
        if (RELU) {
            v0.x = fmaxf(v0.x, 0.f); v0.y = fmaxf(v0.y, 0.f); v0.z = fmaxf(v0.z, 0.f); v0.w = fmaxf(v0.w, 0.f);
            v1.x = fmaxf(v1.x, 0.f); v1.y = fmaxf(v1.y, 0.f); v1.z = fmaxf(v1.z, 0.f); v1.w = fmaxf(v1.w, 0.f);
        }
        int c0 = n0 + (tx << 2), c1 = n0 + 64 + (tx << 2);
        if (c0 < Nstore) *(float4*)(outp + (size_t)mm * out_stride + c0) = v0;
        if (c1 < Nstore) *(float4*)(outp + (size_t)mm * out_stride + c1) = v1;
    }
}

// ---------------- split-K reduce ----------------
__global__ __launch_bounds__(256) void k_reduce(const float* __restrict__ part, float* __restrict__ out, int M, int N, int ks, int relu) {
    int e = blockIdx.x * 256 + threadIdx.x;
    if (e >= M * N) return;
    int m = e / N, n = e - m * N;
    float s = 0.f;
    for (int k = 0; k < ks; ++k) s += part[((size_t)k * 128 + m) * N + n];
    if (relu) s = fmaxf(s, 0.f);
    out[(size_t)m * N + n] = s;
}

// ---------------- rpn decode + hist (merged) ----------------
__global__ __launch_bounds__(256) void k_decodehist(const float* __restrict__ rpno, float* __restrict__ obj,
                                                    float* __restrict__ boxes, unsigned int* __restrict__ hist) {
    int e = blockIdx.x * 256 + threadIdx.x;
    if (e >= NANCH) return;
    int a = e / FHW; int p = e - a * FHW;
    int y = p / FW, x = p - y * FW;
    const float* rp = rpno + (size_t)p * 16;
    float objv = rp[a];
    float dx = rp[3 + a * 4 + 0], dy = rp[3 + a * 4 + 1];
    float dw = rp[3 + a * 4 + 2], dh = rp[3 + a * 4 + 3];
    float sz = (a == 0) ? 32.f : ((a == 1) ? 64.f : 128.f);
    float cxa = (x + 0.5f) * 4.f, cya = (y + 0.5f) * 4.f;
    const float clipv = 4.135166556742356f;
    dw = fminf(dw, clipv); dh = fminf(dh, clipv);
    float cx = dx * sz + cxa, cy = dy * sz + cya;
    float wv = expf(dw) * sz, hv = expf(dh) * sz;
    float x1 = fminf(fmaxf(cx - wv * 0.5f, 0.f), 1215.f);
    float y1 = fminf(fmaxf(cy - hv * 0.5f, 0.f), 799.f);
    float x2 = fminf(fmaxf(cx + wv * 0.5f, 0.f), 1215.f);
    float y2 = fminf(fmaxf(cy + hv * 0.5f, 0.f), 799.f);
    obj[e] = objv;
    *(float4*)(boxes + (size_t)e * 4) = make_float4(x1, y1, x2, y2);
    unsigned int u = sortable_f(objv);
    atomicAdd(&hist[u >> 16], 1u);
}

// ---------------- top-1000 ----------------
__global__ __launch_bounds__(1024) void k_cutoff(const unsigned int* __restrict__ hist, unsigned int* __restrict__ cut) {
    __shared__ unsigned int S[1024];
    int t = threadIdx.x;
    int lo = 65536 - 64 * (t + 1);
    unsigned int s = 0;
    for (int b = 0; b < 64; ++b) s += hist[lo + b];
    S[t] = s;
    __syncthreads();
    for (int off = 1; off < 1024; off <<= 1) {
        unsigned int add = (t >= off) ? S[t - off] : 0u;
        __syncthreads();
        S[t] += add;
        __syncthreads();
    }
    unsigned int incl = S[t], excl = incl - s;
    if (excl < 1000u && incl >= 1000u) {
        unsigned int cum = excl;
        int bin = 65536 - 64 * t - 1;
        unsigned int cutbin = 0;
        for (int b = 0; b < 64; ++b) {
            cum += hist[bin - b];
            if (cum >= 1000u) { cutbin = (unsigned int)(bin - b); break; }
        }
        cut[0] = cutbin;
    }
}

__global__ __launch_bounds__(256) void k_compact(const float* __restrict__ obj, const unsigned int* __restrict__ cut,
                                                 unsigned int* __restrict__ cnt, unsigned long long* __restrict__ cand) {
    int e = blockIdx.x * 256 + threadIdx.x;
    if (e >= NANCH) return;
    unsigned int u = sortable_f(obj[e]);
    if ((u >> 16) >= cut[0]) {
        unsigned int pos = atomicAdd(cnt, 1u);
        if (pos < 4096u) cand[pos] = (((unsigned long long)u) << 32) | (unsigned int)(~e);
    }
}

__global__ __launch_bounds__(1024) void k_sort(const unsigned int* __restrict__ cnt, const unsigned long long* __restrict__ cand,
                                               const float* __restrict__ obj, const float* __restrict__ boxes,
                                               float* __restrict__ tops, float* __restrict__ topb) {
    __shared__ unsigned long long sd[4096];
    int t = threadIdx.x;
    int n = (int)cnt[0]; if (n > 4096) n = 4096;
    int sz = (n <= 2048) ? 2048 : 4096;
    for (int i = t; i < sz; i += 1024) sd[i] = (i < n) ? cand[i] : 0ULL;
    __syncthreads();
    for (int k = 2; k <= sz; k <<= 1)
        for (int j = k >> 1; j > 0; j >>= 1) {
            for (int q = t; q < (sz >> 1); q += 1024) {
                int i = 2 * q - (q & (j - 1));
                int ix = i | j;
                unsigned long long a = sd[i], b = sd[ix];
                bool desc = ((i & k) == 0);
                if (desc ? (a < b) : (a > b)) { sd[i] = b; sd[ix] = a; }
            }
            __syncthreads();
        }
    if (t < PRE) {
        unsigned long long key = sd[t];
        unsigned int idx = ~(unsigned int)(key & 0xFFFFFFFFULL);
        tops[t] = obj[idx];
        *(float4*)(topb + (size_t)t * 4) = *(const float4*)(boxes + (size_t)idx * 4);
    }
}

// ---------------- NMS: IoU bitmask + single-wave walk ----------------
__global__ __launch_bounds__(1024) void k_ioumask(const float* __restrict__ topb,
                                                  unsigned long long* __restrict__ iomask) {
    int i = blockIdx.x;
    int j = threadIdx.x;
    float4 bi = *(const float4*)(topb + (size_t)i * 4);
    float areai = (bi.z - bi.x) * (bi.w - bi.y);
    bool sup = false;
    if (j < PRE) {
        float4 bj = *(const float4*)(topb + (size_t)j * 4);
        float areaj = (bj.z - bj.x) * (bj.w - bj.y);
        float ltx = fmaxf(bi.x, bj.x), lty = fmaxf(bi.y, bj.y);
        float rbx = fminf(bi.z, bj.z), rby = fminf(bi.w, bj.w);
        float iw = fmaxf(rbx - ltx, 0.f), ih = fmaxf(rby - lty, 0.f);
        float inter = iw * ih;
        float iou = inter / (areai + areaj - inter + 1e-6f);
        sup = iou > NMS_T;
    }
    unsigned long long m = __ballot(sup);
    if ((j & 63) == 0) iomask[(size_t)i * 16 + (j >> 6)] = m;
}

__global__ __launch_bounds__(64) void k_nmswalk(const unsigned long long* __restrict__ iomask,
                                                const float* __restrict__ topb,
                                                int* __restrict__ keep, int* __restrict__ validi, float* __restrict__ validf,
                                                float* __restrict__ rois, float* __restrict__ outRois) {
    int lane = threadIdx.x;
    __shared__ int keepL[POST];
    __shared__ int valL[POST];
    unsigned long long aw = 0ULL;
    if (lane < 16) aw = (lane == 15) ? 0x000000FFFFFFFFFFULL : ~0ULL;
    for (int it = 0; it < POST; ++it) {
        unsigned long long nz = __ballot(aw != 0ULL);
        int s, ok;
        if (nz == 0ULL) { s = 0; ok = 0; }
        else {
            int fl = __ffsll((unsigned long long)nz) - 1;
            unsigned long long w0 = __shfl(aw, fl, 64);
            int bit = __ffsll(w0) - 1;
            s = fl * 64 + bit; ok = 1;
        }
        if (lane == 0) { keepL[it] = s; valL[it] = ok; }
        if (lane < 16) {
            if (!ok) aw = 0ULL;
            else aw &= ~iomask[(size_t)s * 16 + lane];
        }
    }
    __syncthreads();
    for (int i = lane; i < POST; i += 64) {
        int kk = keepL[i]; int ok = valL[i];
        float vf = ok ? 1.f : 0.f;
        keep[i] = kk; validi[i] = ok; validf[i] = vf;
        float4 b = *(const float4*)(topb + (size_t)kk * 4);
        float4 r4 = make_float4(b.x * vf, b.y * vf, b.z * vf, b.w * vf);
        *(float4*)(rois + (size_t)i * 4) = r4;
        *(float4*)(outRois + (size_t)i * 4) = r4;
    }
}

// ---------------- RoIAlign from split planes ----------------
// OUTM 0: fp32 ; 2: hi-plane only
template<int P, int OUTM>
__global__ __launch_bounds__(256) void k_roialign(const u16* __restrict__ fh, const u16* __restrict__ fl,
                                                  const float* __restrict__ rois,
                                                  float* __restrict__ outF, u16* __restrict__ oh) {
    const int S = 2 * P;
    int b = blockIdx.x;
    int pyx = blockIdx.y;
    int py = pyx / P, px = pyx - py * P;
    int c = threadIdx.x;
    const float* r = rois + (size_t)b * 4;
    float x1 = r[0] * 0.25f, y1 = r[1] * 0.25f, x2 = r[2] * 0.25f, y2 = r[3] * 0.25f;
    float h = fmaxf(y2 - y1, 1.f), w = fmaxf(x2 - x1, 1.f);
    float acc = 0.f;
    for (int sy = 2 * py; sy < 2 * py + 2; ++sy)
        for (int sx = 2 * px; sx < 2 * px + 2; ++sx) {
            float ys = y1 + (sy + 0.5f) * (h / (float)S);
            float xs = x1 + (sx + 0.5f) * (w / (float)S);
            float y0f = floorf(ys), x0f = floorf(xs);
            float ly = ys - y0f, lx = xs - x0f;
            int y0 = min(max((int)y0f, 0), FH - 1);
            int y1i = min(max((int)y0f + 1, 0), FH - 1);
            int x0 = min(max((int)x0f, 0), FW - 1);
            int x1i = min(max((int)x0f + 1, 0), FW - 1);
            size_t i00 = ((size_t)(y0 * FW + x0)) * 256 + c;
            size_t i01 = ((size_t)(y0 * FW + x1i)) * 256 + c;
            size_t i10 = ((size_t)(y1i * FW + x0)) * 256 + c;
            size_t i11 = ((size_t)(y1i * FW + x1i)) * 256 + c;
            float f00 = bff(fh[i00]) + bff(fl[i00]);
            float f01 = bff(fh[i01]) + bff(fl[i01]);
            float f10 = bff(fh[i10]) + bff(fl[i10]);
            float f11 = bff(fh[i11]) + bff(fl[i11]);
            acc += f00 * (1.f - ly) * (1.f - lx) + f01 * (1.f - ly) * lx + f10 * ly * (1.f - lx) + f11 * ly * lx;
        }
    float v = acc * 0.25f;
    size_t oi = ((size_t)((b * P + py) * P + px)) * 256 + c;
    if constexpr (OUTM == 0) outF[oi] = v;
    else oh[oi] = bf16r(v);
}

// ---------------- softmax + scores + labels ----------------
__global__ __launch_bounds__(64) void k_softmax(const float* __restrict__ logits, const int* __restrict__ validi,
                                                const float* __restrict__ validf, int* __restrict__ labOut,
                                                float* __restrict__ dout) {
    int b = blockIdx.x, t = threadIdx.x;
    const float* L = logits + (size_t)b * 128;
    float l0 = (t < 81) ? L[t] : -INFINITY;
    float l1 = (t + 64 < 81) ? L[t + 64] : -INFINITY;
    float mx = fmaxf(l0, l1);
    for (int off = 32; off > 0; off >>= 1) mx = fmaxf(mx, __shfl_xor(mx, off, 64));
    float e0 = expf(l0 - mx), e1 = expf(l1 - mx);
    float sum = e0 + e1;
    for (int off = 32; off > 0; off >>= 1) sum += __shfl_xor(sum, off, 64);
    float fv = (t >= 1 && t < 81) ? l0 : -INFINITY;
    int fi = t;
    float fv2 = (t + 64 < 81) ? l1 : -INFINITY;
    if (fv2 > fv || (fv2 == fv && (t + 64) < fi)) { fv = fv2; fi = t + 64; }
    for (int off = 32; off > 0; off >>= 1) {
        float ov = __shfl_xor(fv, off, 64);
        int oi = __shfl_xor(fi, off, 64);
        if (ov > fv || (ov == fv && oi < fi)) { fv = ov; fi = oi; }
    }
    if (t == 0) {
        float prob = expf(fv - mx) / sum;
        int vi = validi[b];
        labOut[b] = fi * vi;
        dout[OUT_LABS + b] = (float)(fi * vi);
        dout[OUT_SC + b] = prob * validf[b];
    }
}

// ---------------- final masks ----------------
__global__ __launch_bounds__(256) void k_masks(const float* __restrict__ dpart, const float* __restrict__ validf,
                                               float* __restrict__ dout) {
    int e = blockIdx.x * 256 + threadIdx.x;
    if (e >= 100 * 28 * 28) return;
    int b = e / 784; int r = e - b * 784;
    int y = r / 28, x = r - y * 28;
    int pyx = (y & 1) * 2 + (x & 1);
    int m = (b * 14 + (y >> 1)) * 14 + (x >> 1);
    float s = dpart[(size_t)(pyx * 2 + 0) * 19600 + m] + dpart[(size_t)(pyx * 2 + 1) * 19600 + m];
    float val = 1.f / (1.f + expf(-s)) * validf[b];
    dout[OUT_MASK + (size_t)b * 784 + y * 28 + x] = val;
}

// ---------------- host ----------------
extern "C" void kernel_launch(void* const* d_in, const int* in_sizes, int n_in,
                              void* d_out, int out_size, void* d_ws, size_t ws_size,
                              hipStream_t stream) {
    const float* image = (const float*)d_in[0];
    const float* stem_w1 = (const float*)d_in[1];
    const float* stem_w2 = (const float*)d_in[2];
    const float* rpn_w = (const float*)d_in[3];
    const float* rpn_cls_w = (const float*)d_in[4];
    const float* rpn_box_w = (const float*)d_in[5];
    const float* fc1_w = (const float*)d_in[6];
    const float* fc2_w = (const float*)d_in[7];
    const float* cls_w = (const float*)d_in[8];
    const float* mask_w1 = (const float*)d_in[9];
    const float* mask_w2 = (const float*)d_in[10];
    const float* mask_w3 = (const float*)d_in[11];
    const float* mask_w4 = (const float*)d_in[12];
    const float* mask_deconv_w = (const float*)d_in[13];
    const float* mask_pred_w = (const float*)d_in[14];
    char* ws = (char*)d_ws;
    float* out = (float*)d_out;

    auto F = [&](size_t b) { return (float*)(ws + b); };
    auto U = [&](size_t b) { return (u16*)(ws + b); };

    unsigned int* cnt = (unsigned int*)(ws + B_CNT);
    unsigned int* cut = (unsigned int*)(ws + B_CUT);
    unsigned int* hist = (unsigned int*)(ws + B_HIST);
    unsigned int* zbuf32 = (unsigned int*)(ws + B_ZBUF);
    const u16* zb = (const u16*)(ws + B_ZBUF);
    unsigned long long* cand = (unsigned long long*)(ws + B_POOL);               // dead before POOL written
    unsigned long long* iomask = (unsigned long long*)(ws + B_POOL + 32768);     // dead before POOL written
    int* keep = (int*)(ws + B_KEEP);
    int* validi = (int*)(ws + B_VALI);
    int* labels = (int*)(ws + B_LAB);

    // all init + weight packing in one launch
    k_packs<<<37628, 256, 0, stream>>>(
        image, stem_w1, stem_w2, rpn_w, rpn_cls_w, rpn_box_w, fc1_w, fc2_w, cls_w,
        mask_w1, mask_w2, mask_w3, mask_w4, mask_deconv_w,
        hist, cnt, zbuf32,
        F(B_WFC2), F(B_WCLS), F(B_WFC1),
        U(B_WSP_S2), U(B_WSP_RPN), U(B_WSP_M1), U(B_WSP_DC), U(B_WRPNH), U(B_WS1),
        U(B_IMGH), U(B_IMGL));

    // backbone (16x16x32 MFMA, r3 structure)
    k_mfma<2, 0, 1, 1, 3><<<dim3(1, 475), 256, 0, stream>>>(
        U(B_IMGH), U(B_IMGL), U(B_WS1), nullptr, U(B_S1H), U(B_S1L), 64, 64,
        FHW, FH, FW, 2, 7, 0, zb, nullptr, nullptr, nullptr, 0);
    k_mfma<1, 0, 1, 1, 3><<<dim3(2, 475), 256, 0, stream>>>(
        U(B_S1H), U(B_S1L), U(B_WSP_S2), nullptr, U(B_FEATH), U(B_FEATL), 256, 256,
        FHW, FH, FW, 6, 18, 0, zb, nullptr, nullptr, nullptr, 0);
    k_mfma<1, 0, 1, 1, 3><<<dim3(2, 475), 256, 0, stream>>>(
        U(B_FEATH), U(B_FEATL), U(B_WSP_RPN), nullptr, U(B_TH), U(B_TL), 256, 256,
        FHW, FH, FW, 8, 72, 0, zb, nullptr, nullptr, nullptr, 0);
    k_rpnhead<<<238, 256, 0, stream>>>(U(B_TH), U(B_TL), rpn_cls_w, rpn_box_w, F(B_RPNO));

    // proposals
    k_decodehist<<<713, 256, 0, stream>>>(F(B_RPNO), F(B_OBJ), F(B_BOX), hist);
    k_cutoff<<<1, 1024, 0, stream>>>(hist, cut);
    k_compact<<<713, 256, 0, stream>>>(F(B_OBJ), cut, cnt, cand);
    k_sort<<<1, 1024, 0, stream>>>(cnt, cand, F(B_OBJ), F(B_BOX), F(B_TOPS), F(B_TOPB));
    k_ioumask<<<PRE, 1024, 0, stream>>>(F(B_TOPB), iomask);
    k_nmswalk<<<1, 64, 0, stream>>>(iomask, F(B_TOPB), keep, validi, F(B_VALF), F(B_ROIS), out + OUT_ROIS);

    // box head
    k_roialign<7, 0><<<dim3(100, 49), 256, 0, stream>>>(U(B_FEATH), U(B_FEATL), F(B_ROIS), F(B_POOL), nullptr);
    k_gemm<1, 0><<<dim3(8, 1, 28), 256, 0, stream>>>(F(B_POOL), F(B_WFC1), F(B_PART), 1024, 1024,
        100, 1024, 28, 12544);
    k_reduce<<<400, 256, 0, stream>>>(F(B_PART), F(B_X1), 100, 1024, 28, 1);
    k_gemm<1, 0><<<dim3(8, 1, 8), 256, 0, stream>>>(F(B_X1), F(B_WFC2), F(B_PART), 1024, 1024,
        100, 1024, 8, 1024);
    k_reduce<<<400, 256, 0, stream>>>(F(B_PART), F(B_X2), 100, 1024, 8, 1);
    k_gemm<1, 0><<<dim3(1, 1, 8), 256, 0, stream>>>(F(B_X2), F(B_WCLS), F(B_PART), 128, 128,
        100, 128, 8, 1024);
    k_reduce<<<50, 256, 0, stream>>>(F(B_PART), F(B_LOG), 100, 128, 8, 0);
    k_softmax<<<100, 64, 0, stream>>>(F(B_LOG), validi, F(B_VALF), labels, out);

    // mask head (convs 1-term bf16 — measured-safe in r5/r6; deconv 2-term)
    k_roialign<14, 2><<<dim3(100, 196), 256, 0, stream>>>(U(B_FEATH), U(B_FEATL), F(B_ROIS), nullptr, U(B_M0H));
    k_mfma<1, 0, 1, 3, 1><<<dim3(2, 154), 256, 0, stream>>>(
        U(B_M0H), nullptr, U(B_WSP_M1), nullptr, U(B_MP1H), nullptr, 256, 256,
        19600, 14, 14, 8, 72, 0, zb, nullptr, nullptr, nullptr, 0);
    k_mfma<1, 0, 1, 3, 1><<<dim3(2, 154), 256, 0, stream>>>(
        U(B_MP1H), nullptr, U(B_WSP_M1) + 1179648, nullptr, U(B_MP2H), nullptr, 256, 256,
        19600, 14, 14, 8, 72, 0, zb, nullptr, nullptr, nullptr, 0);
    k_mfma<1, 0, 1, 3, 1><<<dim3(2, 154), 256, 0, stream>>>(
        U(B_MP2H), nullptr, U(B_WSP_M1) + 2 * 1179648, nullptr, U(B_MP1H), nullptr, 256, 256,
        19600, 14, 14, 8, 72, 0, zb, nullptr, nullptr, nullptr, 0);
    k_mfma<1, 0, 1, 3, 1><<<dim3(2, 154), 256, 0, stream>>>(
        U(B_MP1H), nullptr, U(B_WSP_M1) + 3 * 1179648, nullptr, U(B_MP2H), nullptr, 256, 256,
        19600, 14, 14, 8, 72, 0, zb, nullptr, nullptr, nullptr, 0);
    k_mfma<0, 2, 0, 0, 2><<<dim3(8, 154), 256, 0, stream>>>(
        U(B_MP2H), nullptr, U(B_WSP_DC), nullptr, nullptr, nullptr, 0, 0,
        19600, 0, 0, 8, 8, 256, zb, labels, mask_pred_w, F(B_DP), 19600);
    k_masks<<<307, 256, 0, stream>>>(F(B_DP), F(B_VALF), out);

    (void)in_sizes; (void)n_in; (void)out_size; (void)ws_size;
}

// Round 9
// 887.827 us; speedup vs baseline: 1.1541x; 1.0386x over previous
//
#include <hip/hip_runtime.h>
#include <cstdint>
#include <cstddef>

constexpr int IMG_H = 800, IMG_W = 1216;
constexpr int FH = 200, FW = 304;
constexpr int FHW = FH * FW;            // 60800
constexpr int NANCH = 3 * FHW;          // 182400
constexpr int PRE = 1000, POST = 100;
constexpr float NMS_T = 0.7f;
constexpr int QH = 803, QW = 1220;      // padded split image dims (c4 inner)

// ---------------- workspace layout (BYTE offsets) ----------------
constexpr size_t B_FEATH = 0;                       // bf16 60800*256
constexpr size_t B_FEATL = 31129600;                // bf16
constexpr size_t B_T     = 62259200;                // overlay region (62MB)
constexpr size_t B_S1H   = B_T;                     // stem1 hi plane
constexpr size_t B_S1L   = B_T + 7782400;
constexpr size_t B_TH    = B_T;                     // rpn t hi plane
constexpr size_t B_TL    = B_T + 31129600;          // rpn t lo plane
constexpr size_t B_PART  = B_T;                     // fp32 56*128*1024 (fc head, 29.4MB)
constexpr size_t B_M0H   = B_T + 31129600;          // mask input plane (10MB) — survives fc phase
constexpr size_t B_MP1H  = B_T;                     // mask ping (10MB)
constexpr size_t B_MP2H  = B_T + 10035200;          // mask pong (10MB)
constexpr size_t B_DP    = B_T + 20070400;          // fp32 8*19600
constexpr size_t B_RPNO  = 124518400;               // fp32 60800*16
constexpr size_t B_OBJ   = 128409600;               // fp32 182400
constexpr size_t B_BOX   = 129139200;               // fp32 182400*4
constexpr size_t B_HIST  = 132057600;               // u32 65536
constexpr size_t B_MISC  = 132319744;               // 64KB misc
constexpr size_t B_POOL  = 132385280;               // fp32 100*49*256 (cand + iomask overlay early)
constexpr size_t B_X1    = 137402880;               // fp32 100*1024
constexpr size_t B_X2    = 137812480;
constexpr size_t B_LOG   = 138222080;               // fp32 100*128
constexpr size_t B_WRPNH = 138273280;               // u16 split rpn-head weights (unused, kept)
constexpr size_t B_WFC2  = 138404352;               // fp32 1024*1024
constexpr size_t B_WCLS  = 142598656;               // fp32 1024*128
constexpr size_t B_WFC1  = 143122944;               // fp32 12544*1024
constexpr size_t B_WSP   = 194503168;               // split weights (bf16)
constexpr size_t B_WSP_S2  = B_WSP;                 // 576*256*4
constexpr size_t B_WSP_RPN = B_WSP_S2 + 589824;     // 2304*256*4
constexpr size_t B_WSP_M1  = B_WSP_RPN + 2359296;   // 4x 1179648
constexpr size_t B_WSP_DC  = B_WSP_M1 + 4 * 1179648;
constexpr size_t B_IMGH  = B_WSP_DC + 1048576;
constexpr size_t B_IMGL  = B_IMGH + 7837280;
constexpr size_t B_WS1   = B_IMGL + 7837280;        // stem1 split weights 114688 B
// MISC sublayout
constexpr size_t B_CNT  = B_MISC + 0;
constexpr size_t B_CUT  = B_MISC + 4;
constexpr size_t B_ZBUF = B_MISC + 256;             // 256B zeros
constexpr size_t B_TOPS = B_MISC + 512;             // 1000 f
constexpr size_t B_TOPB = B_MISC + 4608;            // 4000 f
constexpr size_t B_KEEP = B_MISC + 20608;           // 100 i
constexpr size_t B_VALI = B_MISC + 21008;
constexpr size_t B_VALF = B_MISC + 21408;
constexpr size_t B_ROIS = B_MISC + 21808;           // 400 f
constexpr size_t B_LAB  = B_MISC + 23408;           // 100 i
// d_out offsets (floats)
constexpr size_t OUT_ROIS = 0, OUT_LABS = 400, OUT_MASK = 500, OUT_SC = 78900;

using f32x4 = __attribute__((ext_vector_type(4))) float;
using s16x8 = __attribute__((ext_vector_type(8))) short;
typedef unsigned short u16;

__device__ __forceinline__ u16 bf16r(float f) {
    unsigned u = __float_as_uint(f);
    return (u16)((u + 0x7FFFu + ((u >> 16) & 1u)) >> 16);
}
__device__ __forceinline__ float bff(u16 h) { return __uint_as_float(((unsigned)h) << 16); }

__device__ __forceinline__ unsigned int sortable_f(float f) {
    unsigned int u = __float_as_uint(f);
    return (u & 0x80000000u) ? ~u : (u | 0x80000000u);
}

// conv3x3 split pack helper
__device__ __forceinline__ void packsplit3_body(int e, const float* __restrict__ w, u16* __restrict__ dst,
                                                int C, int clog2, int nks) {
    int j = e & 7, col = (e >> 3) & 127, kblk = (e >> 10) & 3;
    int g = e >> 12; int ks = g % nks; int nt = g / nks;
    int k = ks * 32 + kblk * 8 + j;
    int o = nt * 128 + col;
    int c = k & (C - 1); int q = k >> clog2;
    int ky = q / 3, kx = q - ky * 3;
    float v = w[(size_t)(o * C + c) * 9 + ky * 3 + kx];
    u16 h = bf16r(v); u16 l = bf16r(v - bff(h));
    size_t base = (size_t)(nt * nks + ks) * 8192 + kblk * 1024 + col * 8 + j;
    dst[base] = h; dst[base + 4096] = l;
}

// ---------------- ALL init + weight packing in ONE kernel ----------------
__global__ __launch_bounds__(256) void k_packs(
    const float* __restrict__ image, const float* __restrict__ stem_w1, const float* __restrict__ stem_w2,
    const float* __restrict__ rpn_w, const float* __restrict__ rpn_cls_w, const float* __restrict__ rpn_box_w,
    const float* __restrict__ fc1_w, const float* __restrict__ fc2_w, const float* __restrict__ cls_w,
    const float* __restrict__ mw0, const float* __restrict__ mw1, const float* __restrict__ mw2,
    const float* __restrict__ mw3, const float* __restrict__ wd,
    unsigned int* __restrict__ hist, unsigned int* __restrict__ cnt, unsigned int* __restrict__ zbuf,
    float* __restrict__ wfc2, float* __restrict__ wcls, float* __restrict__ wfc1,
    u16* __restrict__ wsp_s2, u16* __restrict__ wsp_rpn, u16* __restrict__ wsp_m, u16* __restrict__ wsp_dc,
    u16* __restrict__ wrpnh, u16* __restrict__ ws1, u16* __restrict__ imgh, u16* __restrict__ imgl)
{
    __shared__ float tile[64][50];
    int b = blockIdx.x, t = threadIdx.x;
    if (b < 256) {
        int i = b * 256 + t;
        if (i < 65536) hist[i] = 0u;
        if (i < 64) zbuf[i] = 0u;
        if (i == 0) cnt[0] = 0u;
    } else if (b < 4352) {          // fc2^T
        int e = (b - 256) * 256 + t;
        int k = e >> 10, n = e & 1023;
        wfc2[e] = fc2_w[(size_t)n * 1024 + k];
    } else if (b < 4864) {          // cls^T pad 128
        int e = (b - 4352) * 256 + t;
        int k = e >> 7, n = e & 127;
        wcls[e] = (n < 81) ? cls_w[(size_t)n * 1024 + k] : 0.f;
    } else if (b < 8960) {          // fc1 transpose
        int bb = b - 4864;
        int c = bb >> 4, n0 = (bb & 15) * 64;
        for (int e = t; e < 64 * 49; e += 256) {
            int nn = e / 49, ss = e - nn * 49;
            tile[nn][ss] = fc1_w[(size_t)(n0 + nn) * 12544 + c * 49 + ss];
        }
        __syncthreads();
        for (int e = t; e < 49 * 64; e += 256) {
            int ss = e >> 6, nn = e & 63;
            wfc1[(size_t)(ss * 256 + c) * 1024 + n0 + nn] = tile[nn][ss];
        }
    } else if (b < 9536) {          // stem2 split
        packsplit3_body((b - 8960) * 256 + t, stem_w2, wsp_s2, 64, 6, 18);
    } else if (b < 11840) {         // rpn split
        packsplit3_body((b - 9536) * 256 + t, rpn_w, wsp_rpn, 256, 8, 72);
    } else if (b < 21056) {         // mask convs x4
        int bb = b - 11840;
        int z = bb / 2304;
        const float* w = (z == 0) ? mw0 : (z == 1) ? mw1 : (z == 2) ? mw2 : mw3;
        packsplit3_body((bb - z * 2304) * 256 + t, w, wsp_m + (size_t)z * 1179648, 256, 8, 72);
    } else if (b < 22080) {         // deconv fused
        int e = (b - 21056) * 256 + t;
        int j = e & 7, col = (e >> 3) & 127, kblk = (e >> 10) & 3;
        int g = e >> 12; int ks = g & 7; int nt = g >> 3;
        int k = ks * 32 + kblk * 8 + j;
        int n = nt * 128 + col;
        int pyx = n >> 8, o = n & 255;
        int py = pyx >> 1, px = pyx & 1;
        float v = wd[(size_t)(o * 256 + k) * 4 + (1 - py) * 2 + (1 - px)];
        u16 h = bf16r(v); u16 l = bf16r(v - bff(h));
        size_t base = (size_t)(nt * 8 + ks) * 8192 + kblk * 1024 + col * 8 + j;
        wsp_dc[base] = h; wsp_dc[base + 4096] = l;
    } else if (b < 22208) {         // rpn head split (unused, kept for range stability)
        int e = (b - 22080) * 256 + t;
        int j = e & 7, col = (e >> 3) & 127, kblk = (e >> 10) & 3, ks = e >> 12;
        int k = ks * 32 + kblk * 8 + j;
        float v = 0.f;
        if (col < 3) v = rpn_cls_w[col * 256 + k];
        else if (col < 15) v = rpn_box_w[(col - 3) * 256 + k];
        u16 h = bf16r(v); u16 l = bf16r(v - bff(h));
        size_t base = (size_t)ks * 8192 + kblk * 1024 + col * 8 + j;
        wrpnh[base] = h; wrpnh[base + 4096] = l;
    } else if (b < 22320) {         // stem1 weights split
        int e = (b - 22208) * 256 + t;
        int j = e & 7, col = (e >> 3) & 127, kblk = (e >> 10) & 3, ks = e >> 12;
        int k = ks * 32 + kblk * 8 + j;
        int ky = k >> 5, kx = (k >> 2) & 7, c = k & 3;
        float v = 0.f;
        if (kx < 7 && c < 3 && col < 64) v = stem_w1[(((size_t)col * 3 + c) * 7 + ky) * 7 + kx];
        u16 h = bf16r(v); u16 l = bf16r(v - bff(h));
        size_t base = (size_t)ks * 8192 + kblk * 1024 + col * 8 + j;
        ws1[base] = h; ws1[base + 4096] = l;
    } else {                        // padded image split
        int e = (b - 22320) * 256 + t;
        if (e < QH * QW * 4) {
            int c = e & 3; int p = e >> 2;
            int xx = p % QW; int yy = p / QW;
            int iy = yy - 1, ix = xx - 1;
            float v = 0.f;
            if (c < 3 && (unsigned)iy < (unsigned)IMG_H && (unsigned)ix < (unsigned)IMG_W)
                v = image[((size_t)c * IMG_H + iy) * IMG_W + ix];
            u16 h = bf16r(v);
            imgh[e] = h; imgl[e] = bf16r(v - bff(h));
        }
    }
}

// ---------------- split-bf16 MFMA GEMM (implicit conv), 16x16x32 inner (r3 structure) ----------------
// A,B staged via LDS, single-buffered, 2 barriers per K-step — measured-best structure.
// MT: m-tile rows (128 or 64). 64 doubles grid for small-M convs (occupancy).
// AMODE 0: flat A rows (stride Kflat); 1: 3x3 SAME im2col HWC (C=1<<clog2); 2: stem1 7x7 s4
// TERMS 3: ah*bh+ah*bl+al*bh ; 2: ah*bh+ah*bl ; 1: ah*bh
// OUTK: 0 fp32, 1 split hi+lo, 3 hi only  (all guard n<nstore)
// EPI 0: store; EPI 2: fused deconv mask-pred partial (MT=128 only)
template<int AMODE, int EPI, int RELU, int OUTK, int TERMS, int MT>
__global__ __launch_bounds__(256) void k_mfma(
    const u16* __restrict__ Ahi, const u16* __restrict__ Alo,
    const u16* __restrict__ Bsp,
    float* __restrict__ outF, u16* __restrict__ outH, u16* __restrict__ outL,
    int ostride, int nstore,
    int M, int H, int W, int clog2, int nks, int Kflat,
    const u16* __restrict__ zb,
    const int* __restrict__ labels, const float* __restrict__ wp,
    float* __restrict__ dpart, int Mtot)
{
    constexpr int APLANE = MT * 32;                      // u16 per A plane
    constexpr int APL = (TERMS == 3) ? 2 * APLANE : APLANE;
    constexpr int BPL = (TERMS >= 2) ? 8192 : 4096;
    constexpr int NI = MT / 32;                          // m-frags per wave
    __shared__ u16 Al[APL];
    __shared__ u16 Bl[BPL];
    __shared__ float scr[2][128];
    const int tid = threadIdx.x;
    // XCD-contiguous bijective swizzle (m204)
    int lin = blockIdx.y * gridDim.x + blockIdx.x;
    int nb = gridDim.x * gridDim.y;
    int qq = nb >> 3, rr = nb & 7;
    int xcd = lin & 7, rkk = lin >> 3;
    int nlin = (xcd < rr ? xcd * (qq + 1) : rr * (qq + 1) + (xcd - rr) * qq) + rkk;
    const int nt = nlin % gridDim.x, mt = nlin / gridDim.x;

    const int m0 = mt * MT, n0 = nt * 128;
    const int w = tid >> 6, lane = tid & 63;
    const int wr = w >> 1, wc = w & 1;
    const int lhi = lane >> 4, llo = lane & 15;

    const int row = (MT == 128) ? (tid & 127) : (tid & 63);
    const int kb0 = (MT == 128) ? (tid >> 7) : (tid >> 6);   // 128: 0..1 (2 loads) ; 64: 0..3 (1 load)
    const int m = m0 + row;
    const bool mv = (m < M);
    int pbase = 0, pi = 0, pj = 0;
    if (AMODE >= 1) {
        int mm = mv ? m : 0;
        int HW = H * W;
        int b = mm / HW; int r2 = mm - b * HW;
        pi = r2 / W; pj = r2 - pi * W;
        pbase = b * HW;
    }

    f32x4 acc[NI][4];
#pragma unroll
    for (int i = 0; i < NI; ++i)
#pragma unroll
        for (int j = 0; j < 4; ++j) acc[i][j] = (f32x4)(0.f);

    int4 rA0, rA1, rA2, rA3, rB0, rB1, rB2, rB3;

    auto loadA = [&](int ks) {
        const u16 *sh, *sl = nullptr;
        if (AMODE == 1) {
            int k0 = ks * 32; int q = k0 >> clog2; int c0 = k0 & ((1 << clog2) - 1);
            int ky = q / 3, kx = q - ky * 3;
            int yy = pi + ky - 1, xx = pj + kx - 1;
            bool ok = mv && (unsigned)yy < (unsigned)H && (unsigned)xx < (unsigned)W;
            size_t off = (((size_t)(pbase + yy * W + xx)) << clog2) + c0 + kb0 * 8;
            sh = ok ? Ahi + off : zb;
            if (TERMS == 3) sl = ok ? Alo + off : zb;
        } else if (AMODE == 2) {
            int kk = ks * 32 + kb0 * 8;
            int ky = kk >> 5;
            int kx0 = (kk >> 2) & 7;
            size_t off = ((size_t)(pi * 4 + ky) * QW + pj * 4 + kx0) * 4;
            sh = Ahi + off;
            if (TERMS == 3) sl = Alo + off;
        } else {
            size_t off = (size_t)(mv ? m : 0) * Kflat + ks * 32 + kb0 * 8;
            sh = mv ? Ahi + off : zb;
            if (TERMS == 3) sl = mv ? Alo + off : zb;
        }
        rA0 = *(const int4*)sh;
        if (MT == 128) rA1 = *(const int4*)(sh + 16);
        if (TERMS == 3) {
            rA2 = *(const int4*)sl;
            if (MT == 128) rA3 = *(const int4*)(sl + 16);
        }
    };
    auto loadB = [&](int ks) {
        const u16* bs = Bsp + ((size_t)(nt * nks + ks)) * 8192;
        rB0 = *(const int4*)(bs + (size_t)tid * 8);
        rB1 = *(const int4*)(bs + (size_t)(tid + 256) * 8);
        if (TERMS >= 2) {
            rB2 = *(const int4*)(bs + (size_t)(tid + 512) * 8);
            rB3 = *(const int4*)(bs + (size_t)(tid + 768) * 8);
        }
    };
    auto stash = [&]() {
        if (MT == 128) {
            *(int4*)&Al[(size_t)((kb0    ) * 128 + row) * 8] = rA0;
            *(int4*)&Al[(size_t)((kb0 + 2) * 128 + row) * 8] = rA1;
            if (TERMS == 3) {
                *(int4*)&Al[APLANE + (size_t)((kb0    ) * 128 + row) * 8] = rA2;
                *(int4*)&Al[APLANE + (size_t)((kb0 + 2) * 128 + row) * 8] = rA3;
            }
        } else {
            *(int4*)&Al[(size_t)tid * 8] = rA0;                       // slot=kb0, row: kb0*64+row == tid
            if (TERMS == 3) *(int4*)&Al[APLANE + (size_t)tid * 8] = rA2;
        }
        *(int4*)&Bl[(size_t)tid * 8] = rB0;
        *(int4*)&Bl[(size_t)(tid + 256) * 8] = rB1;
        if (TERMS >= 2) {
            *(int4*)&Bl[(size_t)(tid + 512) * 8] = rB2;
            *(int4*)&Bl[(size_t)(tid + 768) * 8] = rB3;
        }
    };

    loadA(0); loadB(0);
    for (int ks = 0; ks < nks; ++ks) {
        if (ks) __syncthreads();
        stash();
        __syncthreads();
        if (ks + 1 < nks) { loadA(ks + 1); loadB(ks + 1); }
        s16x8 fAh[NI], fAl2[NI], fBh[4], fBl[4];
#pragma unroll
        for (int i = 0; i < NI; ++i) {
            int ar = wr * (MT / 2) + i * 16 + llo;
            fAh[i]  = *(const s16x8*)&Al[(size_t)(lhi * MT + ar) * 8];
            if (TERMS == 3) fAl2[i] = *(const s16x8*)&Al[APLANE + (size_t)(lhi * MT + ar) * 8];
        }
#pragma unroll
        for (int j = 0; j < 4; ++j) {
            int bc = wc * 64 + j * 16 + llo;
            fBh[j] = *(const s16x8*)&Bl[(size_t)(lhi * 128 + bc) * 8];
            if (TERMS >= 2) fBl[j] = *(const s16x8*)&Bl[4096 + (size_t)(lhi * 128 + bc) * 8];
        }
#pragma unroll
        for (int i = 0; i < NI; ++i)
#pragma unroll
            for (int j = 0; j < 4; ++j) {
                acc[i][j] = __builtin_amdgcn_mfma_f32_16x16x32_bf16(fAh[i],  fBh[j], acc[i][j], 0, 0, 0);
                if (TERMS >= 2)
                    acc[i][j] = __builtin_amdgcn_mfma_f32_16x16x32_bf16(fAh[i],  fBl[j], acc[i][j], 0, 0, 0);
                if (TERMS == 3)
                    acc[i][j] = __builtin_amdgcn_mfma_f32_16x16x32_bf16(fAl2[i], fBh[j], acc[i][j], 0, 0, 0);
            }
    }

    if (EPI == 0) {
#pragma unroll
        for (int i = 0; i < NI; ++i)
#pragma unroll
            for (int j = 0; j < 4; ++j) {
                f32x4 v = acc[i][j];
                int n = n0 + wc * 64 + j * 16 + llo;
                if (n >= nstore) continue;
#pragma unroll
                for (int r = 0; r < 4; ++r) {
                    int mm = m0 + wr * (MT / 2) + i * 16 + lhi * 4 + r;
                    if (mm < M) {
                        float val = RELU ? fmaxf(v[r], 0.f) : v[r];
                        if constexpr (OUTK == 0) {
                            outF[(size_t)mm * ostride + n] = val;
                        } else if constexpr (OUTK == 1) {
                            u16 h = bf16r(val);
                            outH[(size_t)mm * ostride + n] = h;
                            outL[(size_t)mm * ostride + n] = bf16r(val - bff(h));
                        } else {
                            outH[(size_t)mm * ostride + n] = bf16r(val);
                        }
                    }
                }
            }
    } else {
        // EPI2: deconv + per-label mask-pred dot (MT=128 instantiations only)
#pragma unroll
        for (int i = 0; i < NI; ++i) {
            int mrow = m0 + wr * (MT / 2) + i * 16 + lhi * 4;
            int b = mrow / 196; if (b > 99) b = 99;
            int lab = labels[b];
            float wv[4];
#pragma unroll
            for (int j = 0; j < 4; ++j)
                wv[j] = wp[lab * 256 + ((n0 + wc * 64 + j * 16 + llo) & 255)];
#pragma unroll
            for (int r = 0; r < 4; ++r) {
                float s = 0.f;
#pragma unroll
                for (int j = 0; j < 4; ++j) s = fmaf(fmaxf(acc[i][j][r], 0.f), wv[j], s);
                s += __shfl_xor(s, 1, 64); s += __shfl_xor(s, 2, 64);
                s += __shfl_xor(s, 4, 64); s += __shfl_xor(s, 8, 64);
                if (llo == 0) scr[wc][wr * (MT / 2) + i * 16 + lhi * 4 + r] = s;
            }
        }
        __syncthreads();
        if (tid < MT) {
            int mm = m0 + tid;
            if (mm < M) dpart[(size_t)nt * Mtot + mm] = scr[0][tid] + scr[1][tid];
        }
    }
}

// ---------------- rpn head: 1x1 conv, 15 outputs, plain VALU (full fp32 from hi+lo) ----------------
__global__ __launch_bounds__(256) void k_rpnhead(const u16* __restrict__ th, const u16* __restrict__ tl,
                                                 const float* __restrict__ wcls, const float* __restrict__ wbox,
                                                 float* __restrict__ rpno) {
    __shared__ float W[15][256];
    int t = threadIdx.x;
    for (int e = t; e < 15 * 256; e += 256) {
        int o = e >> 8, k = e & 255;
        W[o][k] = (o < 3) ? wcls[o * 256 + k] : wbox[(o - 3) * 256 + k];
    }
    __syncthreads();
    int p = blockIdx.x * 256 + t;
    if (p >= FHW) return;
    const u16* ph = th + (size_t)p * 256;
    const u16* pl = tl + (size_t)p * 256;
    float acc[15];
#pragma unroll
    for (int o = 0; o < 15; ++o) acc[o] = 0.f;
    for (int k0 = 0; k0 < 256; k0 += 8) {
        s16x8 vh = *(const s16x8*)(ph + k0);
        s16x8 vl = *(const s16x8*)(pl + k0);
        float v[8];
#pragma unroll
        for (int j = 0; j < 8; ++j) v[j] = bff((u16)vh[j]) + bff((u16)vl[j]);
#pragma unroll
        for (int o = 0; o < 15; ++o) {
            float s = acc[o];
#pragma unroll
            for (int j = 0; j < 8; ++j) s = fmaf(v[j], W[o][k0 + j], s);
            acc[o] = s;
        }
    }
    float* rp = rpno + (size_t)p * 16;
#pragma unroll
    for (int o = 0; o < 15; ++o) rp[o] = acc[o];
    rp[15] = 0.f;
}

// ---------------- generic fp32 tile GEMM (fc head, split-K) ----------------
template<int EPI, int RELU>
__global__ __launch_bounds__(256, 2) void k_gemm(
    const float* __restrict__ Ap, const float* __restrict__ Bp,
    float* __restrict__ outp, int out_stride, int Nstore,
    int M, int Npad, int ksteps, int Kflat)
{
    __shared__ float As[16][128];
    __shared__ float Bs[16][128];
    const int tid = threadIdx.x;
    const int nt = blockIdx.x, mt = blockIdx.y, kz = blockIdx.z;
    const int m0 = mt * 128, n0 = nt * 128;
    const int ty = tid >> 4, tx = tid & 15;
    const int am = tid >> 1;
    const int kl = (tid & 1) << 3;
    const int m_g = m0 + am;
    const bool mval = (m_g < M);
    const float* aRow = Ap + (size_t)(mval ? m_g : 0) * Kflat;
    float acc[8][8];
#pragma unroll
    for (int i = 0; i < 8; ++i)
#pragma unroll
        for (int j = 0; j < 8; ++j) acc[i][j] = 0.f;
    const int kbeg = kz * ksteps * 16;
    for (int s = 0; s < ksteps; ++s) {
        const int k0 = kbeg + s * 16;
        float4 v0, v1;
        const int kk = k0 + kl;
        if (mval) {
            v0 = *(const float4*)(aRow + kk);
            v1 = *(const float4*)(aRow + kk + 4);
        } else { v0 = make_float4(0.f, 0.f, 0.f, 0.f); v1 = v0; }
        As[kl + 0][am] = v0.x; As[kl + 1][am] = v0.y; As[kl + 2][am] = v0.z; As[kl + 3][am] = v0.w;
        As[kl + 4][am] = v1.x; As[kl + 5][am] = v1.y; As[kl + 6][am] = v1.z; As[kl + 7][am] = v1.w;
        {
            const float* p = Bp + (size_t)(k0 + ty) * Npad + n0 + (tx << 3);
            float4 b0 = *(const float4*)p;
            float4 b1 = *(const float4*)(p + 4);
            *(float4*)&Bs[ty][(tx << 3)] = b0;
            *(float4*)&Bs[ty][(tx << 3) + 4] = b1;
        }
        __syncthreads();
#pragma unroll
        for (int k = 0; k < 16; ++k) {
            float4 a0 = *(const float4*)&As[k][(ty << 3)];
            float4 a1 = *(const float4*)&As[k][(ty << 3) + 4];
            float4 b0 = *(const float4*)&Bs[k][(tx << 2)];
            float4 b1 = *(const float4*)&Bs[k][64 + (tx << 2)];
            float av[8] = {a0.x, a0.y, a0.z, a0.w, a1.x, a1.y, a1.z, a1.w};
            float bv[8] = {b0.x, b0.y, b0.z, b0.w, b1.x, b1.y, b1.z, b1.w};
#pragma unroll
            for (int i = 0; i < 8; ++i)
#pragma unroll
                for (int j = 0; j < 8; ++j)
                    acc[i][j] = fmaf(av[i], bv[j], acc[i][j]);
        }
        __syncthreads();
    }
#pragma unroll
    for (int i = 0; i < 8; ++i) {
        int ml = (ty << 3) + i;
        int mm = (EPI == 1) ? (kz * 128 + ml) : (m0 + ml);
        bool mok = (EPI == 1) ? true : (mm < M);
        if (!mok) continue;
        float4 v0 = make_float4(acc[i][0], acc[i][1], acc[i][2], acc[i][3]);
        float4 v1 = make_float4(acc[i][4], acc[i][5], acc[i][6], acc[i][7]);
        if (RELU) {
            v0.x = fmaxf(v0.x, 0.f); v0.y = fmaxf(v0.y, 0.f); v0.z = fmaxf(v0.z, 0.f); v0.w = fmaxf(v0.w, 0.f);
            v1.x = fmaxf(v1.x, 0.f); v1.y = fmaxf(v1.y, 0.f); v1.z = fmaxf(v1.z, 0.f); v1.w = fmaxf(v1.w, 0.f);
        }
        int c0 = n0 + (tx << 2), c1 = n0 + 64 + (tx << 2);
        if (c0 < Nstore) *(float4*)(outp + (size_t)mm * out_stride + c0) = v0;
        if (c1 < Nstore) *(float4*)(outp + (size_t)mm * out_stride + c1) = v1;
    }
}

// ---------------- split-K reduce ----------------
__global__ __launch_bounds__(256) void k_reduce(const float* __restrict__ part, float* __restrict__ out, int M, int N, int ks, int relu) {
    int e = blockIdx.x * 256 + threadIdx.x;
    if (e >= M * N) return;
    int m = e / N, n = e - m * N;
    float s = 0.f;
    for (int k = 0; k < ks; ++k) s += part[((size_t)k * 128 + m) * N + n];
    if (relu) s = fmaxf(s, 0.f);
    out[(size_t)m * N + n] = s;
}

// ---------------- rpn decode + hist (merged) ----------------
__global__ __launch_bounds__(256) void k_decodehist(const float* __restrict__ rpno, float* __restrict__ obj,
                                                    float* __restrict__ boxes, unsigned int* __restrict__ hist) {
    int e = blockIdx.x * 256 + threadIdx.x;
    if (e >= NANCH) return;
    int a = e / FHW; int p = e - a * FHW;
    int y = p / FW, x = p - y * FW;
    const float* rp = rpno + (size_t)p * 16;
    float objv = rp[a];
    float dx = rp[3 + a * 4 + 0], dy = rp[3 + a * 4 + 1];
    float dw = rp[3 + a * 4 + 2], dh = rp[3 + a * 4 + 3];
    float sz = (a == 0) ? 32.f : ((a == 1) ? 64.f : 128.f);
    float cxa = (x + 0.5f) * 4.f, cya = (y + 0.5f) * 4.f;
    const float clipv = 4.135166556742356f;
    dw = fminf(dw, clipv); dh = fminf(dh, clipv);
    float cx = dx * sz + cxa, cy = dy * sz + cya;
    float wv = expf(dw) * sz, hv = expf(dh) * sz;
    float x1 = fminf(fmaxf(cx - wv * 0.5f, 0.f), 1215.f);
    float y1 = fminf(fmaxf(cy - hv * 0.5f, 0.f), 799.f);
    float x2 = fminf(fmaxf(cx + wv * 0.5f, 0.f), 1215.f);
    float y2 = fminf(fmaxf(cy + hv * 0.5f, 0.f), 799.f);
    obj[e] = objv;
    *(float4*)(boxes + (size_t)e * 4) = make_float4(x1, y1, x2, y2);
    unsigned int u = sortable_f(objv);
    atomicAdd(&hist[u >> 16], 1u);
}

// ---------------- top-1000 ----------------
__global__ __launch_bounds__(1024) void k_cutoff(const unsigned int* __restrict__ hist, unsigned int* __restrict__ cut) {
    __shared__ unsigned int S[1024];
    int t = threadIdx.x;
    int lo = 65536 - 64 * (t + 1);
    unsigned int s = 0;
    for (int b = 0; b < 64; ++b) s += hist[lo + b];
    S[t] = s;
    __syncthreads();
    for (int off = 1; off < 1024; off <<= 1) {
        unsigned int add = (t >= off) ? S[t - off] : 0u;
        __syncthreads();
        S[t] += add;
        __syncthreads();
    }
    unsigned int incl = S[t], excl = incl - s;
    if (excl < 1000u && incl >= 1000u) {
        unsigned int cum = excl;
        int bin = 65536 - 64 * t - 1;
        unsigned int cutbin = 0;
        for (int b = 0; b < 64; ++b) {
            cum += hist[bin - b];
            if (cum >= 1000u) { cutbin = (unsigned int)(bin - b); break; }
        }
        cut[0] = cutbin;
    }
}

__global__ __launch_bounds__(256) void k_compact(const float* __restrict__ obj, const unsigned int* __restrict__ cut,
                                                 unsigned int* __restrict__ cnt, unsigned long long* __restrict__ cand) {
    int e = blockIdx.x * 256 + threadIdx.x;
    if (e >= NANCH) return;
    unsigned int u = sortable_f(obj[e]);
    if ((u >> 16) >= cut[0]) {
        unsigned int pos = atomicAdd(cnt, 1u);
        if (pos < 4096u) cand[pos] = (((unsigned long long)u) << 32) | (unsigned int)(~e);
    }
}

__global__ __launch_bounds__(1024) void k_sort(const unsigned int* __restrict__ cnt, const unsigned long long* __restrict__ cand,
                                               const float* __restrict__ obj, const float* __restrict__ boxes,
                                               float* __restrict__ tops, float* __restrict__ topb) {
    __shared__ unsigned long long sd[4096];
    int t = threadIdx.x;
    int n = (int)cnt[0]; if (n > 4096) n = 4096;
    int sz = (n <= 2048) ? 2048 : 4096;
    for (int i = t; i < sz; i += 1024) sd[i] = (i < n) ? cand[i] : 0ULL;
    __syncthreads();
    for (int k = 2; k <= sz; k <<= 1)
        for (int j = k >> 1; j > 0; j >>= 1) {
            for (int q = t; q < (sz >> 1); q += 1024) {
                int i = 2 * q - (q & (j - 1));
                int ix = i | j;
                unsigned long long a = sd[i], b = sd[ix];
                bool desc = ((i & k) == 0);
                if (desc ? (a < b) : (a > b)) { sd[i] = b; sd[ix] = a; }
            }
            __syncthreads();
        }
    if (t < PRE) {
        unsigned long long key = sd[t];
        unsigned int idx = ~(unsigned int)(key & 0xFFFFFFFFULL);
        tops[t] = obj[idx];
        *(float4*)(topb + (size_t)t * 4) = *(const float4*)(boxes + (size_t)idx * 4);
    }
}

// ---------------- NMS: IoU bitmask + single-wave walk ----------------
__global__ __launch_bounds__(1024) void k_ioumask(const float* __restrict__ topb,
                                                  unsigned long long* __restrict__ iomask) {
    int i = blockIdx.x;
    int j = threadIdx.x;
    float4 bi = *(const float4*)(topb + (size_t)i * 4);
    float areai = (bi.z - bi.x) * (bi.w - bi.y);
    bool sup = false;
    if (j < PRE) {
        float4 bj = *(const float4*)(topb + (size_t)j * 4);
        float areaj = (bj.z - bj.x) * (bj.w - bj.y);
        float ltx = fmaxf(bi.x, bj.x), lty = fmaxf(bi.y, bj.y);
        float rbx = fminf(bi.z, bj.z), rby = fminf(bi.w, bj.w);
        float iw = fmaxf(rbx - ltx, 0.f), ih = fmaxf(rby - lty, 0.f);
        float inter = iw * ih;
        float iou = inter / (areai + areaj - inter + 1e-6f);
        sup = iou > NMS_T;
    }
    unsigned long long m = __ballot(sup);
    if ((j & 63) == 0) iomask[(size_t)i * 16 + (j >> 6)] = m;
}

__global__ __launch_bounds__(64) void k_nmswalk(const unsigned long long* __restrict__ iomask,
                                                const float* __restrict__ topb,
                                                int* __restrict__ keep, int* __restrict__ validi, float* __restrict__ validf,
                                                float* __restrict__ rois, float* __restrict__ outRois) {
    int lane = threadIdx.x;
    __shared__ int keepL[POST];
    __shared__ int valL[POST];
    unsigned long long aw = 0ULL;
    if (lane < 16) aw = (lane == 15) ? 0x000000FFFFFFFFFFULL : ~0ULL;
    for (int it = 0; it < POST; ++it) {
        unsigned long long nz = __ballot(aw != 0ULL);
        int s, ok;
        if (nz == 0ULL) { s = 0; ok = 0; }
        else {
            int fl = __ffsll((unsigned long long)nz) - 1;
            unsigned long long w0 = __shfl(aw, fl, 64);
            int bit = __ffsll(w0) - 1;
            s = fl * 64 + bit; ok = 1;
        }
        if (lane == 0) { keepL[it] = s; valL[it] = ok; }
        if (lane < 16) {
            if (!ok) aw = 0ULL;
            else aw &= ~iomask[(size_t)s * 16 + lane];
        }
    }
    __syncthreads();
    for (int i = lane; i < POST; i += 64) {
        int kk = keepL[i]; int ok = valL[i];
        float vf = ok ? 1.f : 0.f;
        keep[i] = kk; validi[i] = ok; validf[i] = vf;
        float4 b = *(const float4*)(topb + (size_t)kk * 4);
        float4 r4 = make_float4(b.x * vf, b.y * vf, b.z * vf, b.w * vf);
        *(float4*)(rois + (size_t)i * 4) = r4;
        *(float4*)(outRois + (size_t)i * 4) = r4;
    }
}

// ---------------- RoIAlign (fused 7 + 14) from split planes ----------------
template<int P, int OUTM>
__device__ __forceinline__ void roialign_one(const u16* __restrict__ fh, const u16* __restrict__ fl,
                                             const float* __restrict__ rois,
                                             float* __restrict__ outF, u16* __restrict__ oh,
                                             int b, int pyx, int c) {
    const int S = 2 * P;
    int py = pyx / P, px = pyx - py * P;
    const float* r = rois + (size_t)b * 4;
    float x1 = r[0] * 0.25f, y1 = r[1] * 0.25f, x2 = r[2] * 0.25f, y2 = r[3] * 0.25f;
    float h = fmaxf(y2 - y1, 1.f), w = fmaxf(x2 - x1, 1.f);
    float acc = 0.f;
    for (int sy = 2 * py; sy < 2 * py + 2; ++sy)
        for (int sx = 2 * px; sx < 2 * px + 2; ++sx) {
            float ys = y1 + (sy + 0.5f) * (h / (float)S);
            float xs = x1 + (sx + 0.5f) * (w / (float)S);
            float y0f = floorf(ys), x0f = floorf(xs);
            float ly = ys - y0f, lx = xs - x0f;
            int y0 = min(max((int)y0f, 0), FH - 1);
            int y1i = min(max((int)y0f + 1, 0), FH - 1);
            int x0 = min(max((int)x0f, 0), FW - 1);
            int x1i = min(max((int)x0f + 1, 0), FW - 1);
            size_t i00 = ((size_t)(y0 * FW + x0)) * 256 + c;
            size_t i01 = ((size_t)(y0 * FW + x1i)) * 256 + c;
            size_t i10 = ((size_t)(y1i * FW + x0)) * 256 + c;
            size_t i11 = ((size_t)(y1i * FW + x1i)) * 256 + c;
            float f00 = bff(fh[i00]) + bff(fl[i00]);
            float f01 = bff(fh[i01]) + bff(fl[i01]);
            float f10 = bff(fh[i10]) + bff(fl[i10]);
            float f11 = bff(fh[i11]) + bff(fl[i11]);
            acc += f00 * (1.f - ly) * (1.f - lx) + f01 * (1.f - ly) * lx + f10 * ly * (1.f - lx) + f11 * ly * lx;
        }
    float v = acc * 0.25f;
    size_t oi = ((size_t)((b * P + py) * P + px)) * 256 + c;
    if constexpr (OUTM == 0) outF[oi] = v;
    else oh[oi] = bf16r(v);
}

__global__ __launch_bounds__(256) void k_roialign2(const u16* __restrict__ fh, const u16* __restrict__ fl,
                                                   const float* __restrict__ rois,
                                                   float* __restrict__ outF, u16* __restrict__ oh) {
    int b = blockIdx.x, q = blockIdx.y, c = threadIdx.x;
    if (q < 49) roialign_one<7, 0>(fh, fl, rois, outF, nullptr, b, q, c);
    else        roialign_one<14, 2>(fh, fl, rois, nullptr, oh, b, q - 49, c);
}

// ---------------- softmax + scores + labels ----------------
__global__ __launch_bounds__(64) void k_softmax(const float* __restrict__ logits, const int* __restrict__ validi,
                                                const float* __restrict__ validf, int* __restrict__ labOut,
                                                float* __restrict__ dout) {
    int b = blockIdx.x, t = threadIdx.x;
    const float* L = logits + (size_t)b * 128;
    float l0 = (t < 81) ? L[t] : -INFINITY;
    float l1 = (t + 64 < 81) ? L[t + 64] : -INFINITY;
    float mx = fmaxf(l0, l1);
    for (int off = 32; off > 0; off >>= 1) mx = fmaxf(mx, __shfl_xor(mx, off, 64));
    float e0 = expf(l0 - mx), e1 = expf(l1 - mx);
    float sum = e0 + e1;
    for (int off = 32; off > 0; off >>= 1) sum += __shfl_xor(sum, off, 64);
    float fv = (t >= 1 && t < 81) ? l0 : -INFINITY;
    int fi = t;
    float fv2 = (t + 64 < 81) ? l1 : -INFINITY;
    if (fv2 > fv || (fv2 == fv && (t + 64) < fi)) { fv = fv2; fi = t + 64; }
    for (int off = 32; off > 0; off >>= 1) {
        float ov = __shfl_xor(fv, off, 64);
        int oi = __shfl_xor(fi, off, 64);
        if (ov > fv || (ov == fv && oi < fi)) { fv = ov; fi = oi; }
    }
    if (t == 0) {
        float prob = expf(fv - mx) / sum;
        int vi = validi[b];
        labOut[b] = fi * vi;
        dout[OUT_LABS + b] = (float)(fi * vi);
        dout[OUT_SC + b] = prob * validf[b];
    }
}

// ---------------- final masks ----------------
__global__ __launch_bounds__(256) void k_masks(const float* __restrict__ dpart, const float* __restrict__ validf,
                                               float* __restrict__ dout) {
    int e = blockIdx.x * 256 + threadIdx.x;
    if (e >= 100 * 28 * 28) return;
    int b = e / 784; int r = e - b * 784;
    int y = r / 28, x = r - y * 28;
    int pyx = (y & 1) * 2 + (x & 1);
    int m = (b * 14 + (y >> 1)) * 14 + (x >> 1);
    float s = dpart[(size_t)(pyx * 2 + 0) * 19600 + m] + dpart[(size_t)(pyx * 2 + 1) * 19600 + m];
    float val = 1.f / (1.f + expf(-s)) * validf[b];
    dout[OUT_MASK + (size_t)b * 784 + y * 28 + x] = val;
}

// ---------------- host ----------------
extern "C" void kernel_launch(void* const* d_in, const int* in_sizes, int n_in,
                              void* d_out, int out_size, void* d_ws, size_t ws_size,
                              hipStream_t stream) {
    const float* image = (const float*)d_in[0];
    const float* stem_w1 = (const float*)d_in[1];
    const float* stem_w2 = (const float*)d_in[2];
    const float* rpn_w = (const float*)d_in[3];
    const float* rpn_cls_w = (const float*)d_in[4];
    const float* rpn_box_w = (const float*)d_in[5];
    const float* fc1_w = (const float*)d_in[6];
    const float* fc2_w = (const float*)d_in[7];
    const float* cls_w = (const float*)d_in[8];
    const float* mask_w1 = (const float*)d_in[9];
    const float* mask_w2 = (const float*)d_in[10];
    const float* mask_w3 = (const float*)d_in[11];
    const float* mask_w4 = (const float*)d_in[12];
    const float* mask_deconv_w = (const float*)d_in[13];
    const float* mask_pred_w = (const float*)d_in[14];
    char* ws = (char*)d_ws;
    float* out = (float*)d_out;

    auto F = [&](size_t b) { return (float*)(ws + b); };
    auto U = [&](size_t b) { return (u16*)(ws + b); };

    unsigned int* cnt = (unsigned int*)(ws + B_CNT);
    unsigned int* cut = (unsigned int*)(ws + B_CUT);
    unsigned int* hist = (unsigned int*)(ws + B_HIST);
    unsigned int* zbuf32 = (unsigned int*)(ws + B_ZBUF);
    const u16* zb = (const u16*)(ws + B_ZBUF);
    unsigned long long* cand = (unsigned long long*)(ws + B_POOL);               // dead before POOL written
    unsigned long long* iomask = (unsigned long long*)(ws + B_POOL + 32768);     // dead before POOL written
    int* keep = (int*)(ws + B_KEEP);
    int* validi = (int*)(ws + B_VALI);
    int* labels = (int*)(ws + B_LAB);

    // all init + weight packing in one launch
    k_packs<<<37628, 256, 0, stream>>>(
        image, stem_w1, stem_w2, rpn_w, rpn_cls_w, rpn_box_w, fc1_w, fc2_w, cls_w,
        mask_w1, mask_w2, mask_w3, mask_w4, mask_deconv_w,
        hist, cnt, zbuf32,
        F(B_WFC2), F(B_WCLS), F(B_WFC1),
        U(B_WSP_S2), U(B_WSP_RPN), U(B_WSP_M1), U(B_WSP_DC), U(B_WRPNH), U(B_WS1),
        U(B_IMGH), U(B_IMGL));

    // backbone (16x16x32 MFMA, r3 structure)
    k_mfma<2, 0, 1, 1, 3, 128><<<dim3(1, 475), 256, 0, stream>>>(
        U(B_IMGH), U(B_IMGL), U(B_WS1), nullptr, U(B_S1H), U(B_S1L), 64, 64,
        FHW, FH, FW, 2, 7, 0, zb, nullptr, nullptr, nullptr, 0);
    k_mfma<1, 0, 1, 1, 3, 128><<<dim3(2, 475), 256, 0, stream>>>(
        U(B_S1H), U(B_S1L), U(B_WSP_S2), nullptr, U(B_FEATH), U(B_FEATL), 256, 256,
        FHW, FH, FW, 6, 18, 0, zb, nullptr, nullptr, nullptr, 0);
    k_mfma<1, 0, 1, 1, 3, 128><<<dim3(2, 475), 256, 0, stream>>>(
        U(B_FEATH), U(B_FEATL), U(B_WSP_RPN), nullptr, U(B_TH), U(B_TL), 256, 256,
        FHW, FH, FW, 8, 72, 0, zb, nullptr, nullptr, nullptr, 0);
    k_rpnhead<<<238, 256, 0, stream>>>(U(B_TH), U(B_TL), rpn_cls_w, rpn_box_w, F(B_RPNO));

    // proposals
    k_decodehist<<<713, 256, 0, stream>>>(F(B_RPNO), F(B_OBJ), F(B_BOX), hist);
    k_cutoff<<<1, 1024, 0, stream>>>(hist, cut);
    k_compact<<<713, 256, 0, stream>>>(F(B_OBJ), cut, cnt, cand);
    k_sort<<<1, 1024, 0, stream>>>(cnt, cand, F(B_OBJ), F(B_BOX), F(B_TOPS), F(B_TOPB));
    k_ioumask<<<PRE, 1024, 0, stream>>>(F(B_TOPB), iomask);
    k_nmswalk<<<1, 64, 0, stream>>>(iomask, F(B_TOPB), keep, validi, F(B_VALF), F(B_ROIS), out + OUT_ROIS);

    // RoIAlign (box 7x7 fp32 + mask 14x14 bf16, fused)
    k_roialign2<<<dim3(100, 245), 256, 0, stream>>>(U(B_FEATH), U(B_FEATL), F(B_ROIS), F(B_POOL), U(B_M0H));

    // box head (fc1 split-K 56)
    k_gemm<1, 0><<<dim3(8, 1, 56), 256, 0, stream>>>(F(B_POOL), F(B_WFC1), F(B_PART), 1024, 1024,
        100, 1024, 14, 12544);
    k_reduce<<<400, 256, 0, stream>>>(F(B_PART), F(B_X1), 100, 1024, 56, 1);
    k_gemm<1, 0><<<dim3(8, 1, 8), 256, 0, stream>>>(F(B_X1), F(B_WFC2), F(B_PART), 1024, 1024,
        100, 1024, 8, 1024);
    k_reduce<<<400, 256, 0, stream>>>(F(B_PART), F(B_X2), 100, 1024, 8, 1);
    k_gemm<1, 0><<<dim3(1, 1, 8), 256, 0, stream>>>(F(B_X2), F(B_WCLS), F(B_PART), 128, 128,
        100, 128, 8, 1024);
    k_reduce<<<50, 256, 0, stream>>>(F(B_PART), F(B_LOG), 100, 128, 8, 0);
    k_softmax<<<100, 64, 0, stream>>>(F(B_LOG), validi, F(B_VALF), labels, out);

    // mask head (convs 1-term bf16, 64-row m-tiles for occupancy; deconv 2-term)
    k_mfma<1, 0, 1, 3, 1, 64><<<dim3(2, 307), 256, 0, stream>>>(
        U(B_M0H), nullptr, U(B_WSP_M1), nullptr, U(B_MP1H), nullptr, 256, 256,
        19600, 14, 14, 8, 72, 0, zb, nullptr, nullptr, nullptr, 0);
    k_mfma<1, 0, 1, 3, 1, 64><<<dim3(2, 307), 256, 0, stream>>>(
        U(B_MP1H), nullptr, U(B_WSP_M1) + 1179648, nullptr, U(B_MP2H), nullptr, 256, 256,
        19600, 14, 14, 8, 72, 0, zb, nullptr, nullptr, nullptr, 0);
    k_mfma<1, 0, 1, 3, 1, 64><<<dim3(2, 307), 256, 0, stream>>>(
        U(B_MP2H), nullptr, U(B_WSP_M1) + 2 * 1179648, nullptr, U(B_MP1H), nullptr, 256, 256,
        19600, 14, 14, 8, 72, 0, zb, nullptr, nullptr, nullptr, 0);
    k_mfma<1, 0, 1, 3, 1, 64><<<dim3(2, 307), 256, 0, stream>>>(
        U(B_MP1H), nullptr, U(B_WSP_M1) + 3 * 1179648, nullptr, U(B_MP2H), nullptr, 256, 256,
        19600, 14, 14, 8, 72, 0, zb, nullptr, nullptr, nullptr, 0);
    k_mfma<0, 2, 0, 0, 2, 128><<<dim3(8, 154), 256, 0, stream>>>(
        U(B_MP2H), nullptr, U(B_WSP_DC), nullptr, nullptr, nullptr, 0, 0,
        19600, 0, 0, 8, 8, 256, zb, labels, mask_pred_w, F(B_DP), 19600);
    k_masks<<<307, 256, 0, stream>>>(F(B_DP), F(B_VALF), out);

    (void)in_sizes; (void)n_in; (void)out_size; (void)ws_size;
}